// Round 1
// baseline (727.309 us; speedup 1.0000x reference)
//
#include <hip/hip_runtime.h>
#include <stdint.h>

#define S_LEN 1024
#define BATCH 8
#define DMODEL 1024
#define NHEAD 16
#define DHEAD 64
#define DFF_N 4096
#define EPS 1e-5f

typedef __attribute__((ext_vector_type(8))) short bf16x8;
typedef __attribute__((ext_vector_type(4))) float f32x4;

__device__ __forceinline__ unsigned short f2bf(float f) {
  union { float f; unsigned u; } x; x.f = f;
  unsigned r = x.u + 0x7FFFu + ((x.u >> 16) & 1u);
  return (unsigned short)(r >> 16);
}

__device__ __forceinline__ void gld_lds16(const void* g, void* l) {
  __builtin_amdgcn_global_load_lds(
      (const __attribute__((address_space(1))) void*)g,
      (__attribute__((address_space(3))) void*)l, 16, 0, 0);
}

// ---------------- weight transpose + fp32->bf16 ----------------
// src (K,N) fp32 row-major  ->  dst (N,K) bf16 row-major
__global__ __launch_bounds__(256) void transpose_cvt(
    const float* __restrict__ src, unsigned short* __restrict__ dst, int K, int N) {
  __shared__ float tile[32][33];
  int n0 = blockIdx.x * 32, k0 = blockIdx.y * 32;
  int tx = threadIdx.x & 31, ty = threadIdx.x >> 5;  // ty 0..7
#pragma unroll
  for (int p = 0; p < 4; ++p)
    tile[ty + p * 8][tx] = src[(long)(k0 + ty + p * 8) * N + n0 + tx];
  __syncthreads();
#pragma unroll
  for (int p = 0; p < 4; ++p)
    dst[(long)(n0 + ty + p * 8) * K + k0 + tx] = f2bf(tile[tx][ty + p * 8]);
}

// ---------------- LayerNorm (row = 1024), fp32 in -> bf16 out ----------------
// permute=1: out row rr = b*S+s reads input at (s*B+b)*D   (S,B,D) -> BS-major
// permute=0: identity (rr row of (S*B, D))
__global__ __launch_bounds__(256) void ln_kernel(
    const float* __restrict__ in, const float* __restrict__ g,
    const float* __restrict__ be, unsigned short* __restrict__ out, int permute) {
  int rr = blockIdx.x;
  long in_off;
  if (permute) { int b = rr >> 10, s = rr & 1023; in_off = ((long)s * BATCH + b) * DMODEL; }
  else in_off = (long)rr * DMODEL;
  int t = threadIdx.x;
  float4 v = *(const float4*)(in + in_off + t * 4);
  float sum = v.x + v.y + v.z + v.w;
#pragma unroll
  for (int m = 1; m < 64; m <<= 1) sum += __shfl_xor(sum, m);
  __shared__ float red[4];
  __shared__ float red2[4];
  int wave = t >> 6, lane = t & 63;
  if (lane == 0) red[wave] = sum;
  __syncthreads();
  sum = red[0] + red[1] + red[2] + red[3];
  float mean = sum * (1.0f / DMODEL);
  float dx = v.x - mean, dy = v.y - mean, dz = v.z - mean, dw = v.w - mean;
  float vs = dx * dx + dy * dy + dz * dz + dw * dw;
#pragma unroll
  for (int m = 1; m < 64; m <<= 1) vs += __shfl_xor(vs, m);
  if (lane == 0) red2[wave] = vs;
  __syncthreads();
  vs = red2[0] + red2[1] + red2[2] + red2[3];
  float rstd = rsqrtf(vs * (1.0f / DMODEL) + EPS);
  float4 gv = *(const float4*)(g + t * 4);
  float4 bv = *(const float4*)(be + t * 4);
  ushort4 pk;
  pk.x = f2bf(dx * rstd * gv.x + bv.x);
  pk.y = f2bf(dy * rstd * gv.y + bv.y);
  pk.z = f2bf(dz * rstd * gv.z + bv.z);
  pk.w = f2bf(dw * rstd * gv.w + bv.w);
  *(ushort4*)(out + (long)rr * DMODEL + t * 4) = pk;
}

// ---------------- GEMM C = A(M,K) @ Bt(N,K)^T, bf16 in, fp32 acc ----------------
#define BM 128
#define BN 128
#define BK 64
#define MODE_QKV 0
#define MODE_OPROJ 1
#define MODE_FFN1 2
#define MODE_FFN2 3

template <int MODE>
__global__ __launch_bounds__(256) void gemm_bt(
    const unsigned short* __restrict__ A, const unsigned short* __restrict__ Bt,
    int M, int N, int K,
    const float* __restrict__ bias0, const float* __restrict__ bias1,
    const float* __restrict__ bias2,
    unsigned short* out_q, unsigned short* out_k, unsigned short* out_vt,
    const float* __restrict__ resid, float* out_f32, unsigned short* out_bf16) {
  __shared__ unsigned short As[BM * BK];
  __shared__ unsigned short Bs[BN * BK];
  int m0 = blockIdx.y * BM, n0 = blockIdx.x * BN;
  int t = threadIdx.x, wave = t >> 6, lane = t & 63;
  int wr = wave >> 1, wc = wave & 1;
  const unsigned short* Ab = A + (long)m0 * K;
  const unsigned short* Bb = Bt + (long)n0 * K;
  f32x4 acc[4][4];
#pragma unroll
  for (int i = 0; i < 4; ++i)
#pragma unroll
    for (int j = 0; j < 4; ++j) acc[i][j] = (f32x4){0.f, 0.f, 0.f, 0.f};

  int lrow = lane >> 3;        // 0..7
  int lcol = (lane & 7) * 8;   // bf16 col base

  auto stage = [&](int kt) {
    long kofs = (long)kt * BK;
#pragma unroll
    for (int j = 0; j < 4; ++j) {
      int rowbase = (j * 4 + wave) * 8;
      gld_lds16(Ab + (long)(rowbase + lrow) * K + kofs + lcol, &As[rowbase * BK]);
      gld_lds16(Bb + (long)(rowbase + lrow) * K + kofs + lcol, &Bs[rowbase * BK]);
    }
  };

  int kt_count = K / BK;
  stage(0);
  for (int kt = 0; kt < kt_count; ++kt) {
    __syncthreads();  // staged tile visible
#pragma unroll
    for (int kk = 0; kk < 2; ++kk) {
      int ko = kk * 32 + 8 * (lane >> 4);
      bf16x8 a[4], b[4];
#pragma unroll
      for (int i = 0; i < 4; ++i)
        a[i] = *(const bf16x8*)&As[(wr * 64 + i * 16 + (lane & 15)) * BK + ko];
#pragma unroll
      for (int j = 0; j < 4; ++j)
        b[j] = *(const bf16x8*)&Bs[(wc * 64 + j * 16 + (lane & 15)) * BK + ko];
#pragma unroll
      for (int i = 0; i < 4; ++i)
#pragma unroll
        for (int j = 0; j < 4; ++j)
          acc[i][j] = __builtin_amdgcn_mfma_f32_16x16x32_bf16(a[i], b[j], acc[i][j], 0, 0, 0);
    }
    __syncthreads();  // all waves done reading before restage
    if (kt + 1 < kt_count) stage(kt + 1);
  }

  // epilogue: C row = (lane>>4)*4+r, col = lane&15 per 16x16 tile
  int rbase = (lane >> 4) << 2;
#pragma unroll
  for (int i = 0; i < 4; ++i) {
#pragma unroll
    for (int j = 0; j < 4; ++j) {
      int mrow = m0 + wr * 64 + i * 16 + rbase;
      int ncol = n0 + wc * 64 + j * 16 + (lane & 15);
      if constexpr (MODE == MODE_QKV) {
        int sel = ncol >> 10, nn = ncol & 1023;
        int h = nn >> 6, dh = nn & 63;
        const float* bptr = (sel == 0) ? bias0 : ((sel == 1) ? bias1 : bias2);
        float bias = bptr[nn];
        if (sel < 2) {
          unsigned short* dst = (sel == 0) ? out_q : out_k;
#pragma unroll
          for (int r = 0; r < 4; ++r) {
            int m = mrow + r; int bb = m >> 10, s = m & 1023;
            dst[(((long)(bb * NHEAD + h)) * S_LEN + s) * DHEAD + dh] = f2bf(acc[i][j][r] + bias);
          }
        } else {
          int m = mrow; int bb = m >> 10, s = m & 1023;
          ushort4 pk;
          pk.x = f2bf(acc[i][j][0] + bias);
          pk.y = f2bf(acc[i][j][1] + bias);
          pk.z = f2bf(acc[i][j][2] + bias);
          pk.w = f2bf(acc[i][j][3] + bias);
          *(ushort4*)&out_vt[(((long)(bb * NHEAD + h)) * DHEAD + dh) * S_LEN + s] = pk;
        }
      } else if constexpr (MODE == MODE_OPROJ) {
        float bias = bias0[ncol];
#pragma unroll
        for (int r = 0; r < 4; ++r) {
          int m = mrow + r; int bb = m >> 10, s = m & 1023;
          long oi = ((long)s * BATCH + bb) * DMODEL + ncol;
          out_f32[oi] = resid[oi] + acc[i][j][r] + bias;
        }
      } else if constexpr (MODE == MODE_FFN1) {
        float bias = bias0[ncol];
#pragma unroll
        for (int r = 0; r < 4; ++r) {
          long m = mrow + r;
          float v = acc[i][j][r] + bias;
          out_bf16[m * (long)N + ncol] = f2bf(v > 0.f ? v : 0.f);
        }
      } else {  // MODE_FFN2
        float bias = bias0[ncol];
#pragma unroll
        for (int r = 0; r < 4; ++r) {
          long m = mrow + r;
          long oi = m * (long)N + ncol;
          out_f32[oi] = resid[oi] + acc[i][j][r] + bias;
        }
      }
    }
  }
}

// ---------------- flash attention: 1 wave = 16 q rows of one (b,h) ----------------
__global__ __launch_bounds__(64) void attn_kernel(
    const unsigned short* __restrict__ qbuf, const unsigned short* __restrict__ kbuf,
    const unsigned short* __restrict__ vtbuf, const float* __restrict__ attn_bias,
    const int* __restrict__ kpm, const float* __restrict__ alpha_p,
    unsigned short* __restrict__ out) {
  int qt = blockIdx.x, h = blockIdx.y, b = blockIdx.z;
  int lane = threadIdx.x;
  int q0 = qt * 16;
  float alpha = alpha_p[0];
  const float scale = 0.125f;  // DH^-0.5
  long bh = (long)(b * NHEAD + h);
  const unsigned short* Q = qbuf + bh * S_LEN * DHEAD;
  const unsigned short* Kp = kbuf + bh * S_LEN * DHEAD;
  const unsigned short* Vt = vtbuf + bh * DHEAD * S_LEN;

  int kg = 8 * (lane >> 4);
  int qrow = q0 + (lane & 15);
  bf16x8 qf0 = *(const bf16x8*)&Q[(long)qrow * DHEAD + kg];
  bf16x8 qf1 = *(const bf16x8*)&Q[(long)qrow * DHEAD + 32 + kg];

  f32x4 oacc[4];
#pragma unroll
  for (int i = 0; i < 4; ++i) oacc[i] = (f32x4){0.f, 0.f, 0.f, 0.f};
  float mrow[4], lrow[4];
#pragma unroll
  for (int r = 0; r < 4; ++r) { mrow[r] = -1e30f; lrow[r] = 0.f; }

  __shared__ unsigned short P[16 * 40];  // 16 rows x 32 keys, padded stride 40 (80B)

  const float* biasb = attn_bias + (long)b * S_LEN;
  const int* maskb = kpm + (long)b * S_LEN;

  for (int k0 = 0; k0 < S_LEN; k0 += 32) {
    f32x4 sacc[2];
    sacc[0] = (f32x4){0.f, 0.f, 0.f, 0.f};
    sacc[1] = (f32x4){0.f, 0.f, 0.f, 0.f};
#pragma unroll
    for (int n = 0; n < 2; ++n) {
      int krow = k0 + n * 16 + (lane & 15);
      bf16x8 kf0 = *(const bf16x8*)&Kp[(long)krow * DHEAD + kg];
      bf16x8 kf1 = *(const bf16x8*)&Kp[(long)krow * DHEAD + 32 + kg];
      sacc[n] = __builtin_amdgcn_mfma_f32_16x16x32_bf16(qf0, kf0, sacc[n], 0, 0, 0);
      sacc[n] = __builtin_amdgcn_mfma_f32_16x16x32_bf16(qf1, kf1, sacc[n], 0, 0, 0);
    }
    float kbias[2]; int kmask[2];
#pragma unroll
    for (int n = 0; n < 2; ++n) {
      int key = k0 + n * 16 + (lane & 15);
      kbias[n] = biasb[key] * alpha;
      kmask[n] = maskb[key];
    }
    float sv[2][4];
#pragma unroll
    for (int n = 0; n < 2; ++n)
#pragma unroll
      for (int r = 0; r < 4; ++r) {
        float x = sacc[n][r] * scale + kbias[n];
        sv[n][r] = kmask[n] ? -1e30f : x;
      }
    float tmax[4];
#pragma unroll
    for (int r = 0; r < 4; ++r) tmax[r] = fmaxf(sv[0][r], sv[1][r]);
#pragma unroll
    for (int m = 1; m < 16; m <<= 1)
#pragma unroll
      for (int r = 0; r < 4; ++r) tmax[r] = fmaxf(tmax[r], __shfl_xor(tmax[r], m));
    float al[4];
#pragma unroll
    for (int r = 0; r < 4; ++r) {
      float mnew = fmaxf(mrow[r], tmax[r]);
      al[r] = __expf(mrow[r] - mnew);
      mrow[r] = mnew;
    }
    float psum[4];
#pragma unroll
    for (int n = 0; n < 2; ++n)
#pragma unroll
      for (int r = 0; r < 4; ++r) sv[n][r] = __expf(sv[n][r] - mrow[r]);
#pragma unroll
    for (int r = 0; r < 4; ++r) psum[r] = sv[0][r] + sv[1][r];
#pragma unroll
    for (int m = 1; m < 16; m <<= 1)
#pragma unroll
      for (int r = 0; r < 4; ++r) psum[r] += __shfl_xor(psum[r], m);
#pragma unroll
    for (int r = 0; r < 4; ++r) lrow[r] = lrow[r] * al[r] + psum[r];
#pragma unroll
    for (int i = 0; i < 4; ++i)
#pragma unroll
      for (int r = 0; r < 4; ++r) oacc[i][r] *= al[r];

    __syncthreads();  // previous PV reads done
#pragma unroll
    for (int n = 0; n < 2; ++n)
#pragma unroll
      for (int r = 0; r < 4; ++r) {
        int row = ((lane >> 4) << 2) + r;
        int col = n * 16 + (lane & 15);
        P[row * 40 + col] = f2bf(sv[n][r]);
      }
    __syncthreads();  // P visible
    bf16x8 pf = *(const bf16x8*)&P[(lane & 15) * 40 + kg];
#pragma unroll
    for (int dt = 0; dt < 4; ++dt) {
      int dh = dt * 16 + (lane & 15);
      bf16x8 vf = *(const bf16x8*)&Vt[(long)dh * S_LEN + k0 + kg];
      oacc[dt] = __builtin_amdgcn_mfma_f32_16x16x32_bf16(pf, vf, oacc[dt], 0, 0, 0);
    }
  }

#pragma unroll
  for (int dt = 0; dt < 4; ++dt)
#pragma unroll
    for (int r = 0; r < 4; ++r) {
      int q = q0 + ((lane >> 4) << 2) + r;
      int dh = dt * 16 + (lane & 15);
      float v = oacc[dt][r] / lrow[r];
      out[((long)(b * S_LEN + q)) * DMODEL + h * DHEAD + dh] = f2bf(v);
    }
}

// ---------------- host launcher ----------------
extern "C" void kernel_launch(void* const* d_in, const int* in_sizes, int n_in,
                              void* d_out, int out_size, void* d_ws, size_t ws_size,
                              hipStream_t stream) {
  const float* x  = (const float*)d_in[0];
  const int* kpm  = (const int*)d_in[1];
  const float* attn_bias = (const float*)d_in[2];
  const float* Wq = (const float*)d_in[3];  const float* bq = (const float*)d_in[4];
  const float* Wk = (const float*)d_in[5];  const float* bk = (const float*)d_in[6];
  const float* Wv = (const float*)d_in[7];  const float* bv = (const float*)d_in[8];
  const float* Wo = (const float*)d_in[9];  const float* bo = (const float*)d_in[10];
  const float* W1 = (const float*)d_in[11]; const float* b1 = (const float*)d_in[12];
  const float* W2 = (const float*)d_in[13]; const float* b2 = (const float*)d_in[14];
  const float* g1 = (const float*)d_in[15]; const float* be1 = (const float*)d_in[16];
  const float* g2 = (const float*)d_in[17]; const float* be2 = (const float*)d_in[18];
  const float* alpha = (const float*)d_in[19];
  float* out = (float*)d_out;

  char* ws = (char*)d_ws;
  size_t off = 0;
  auto alloc = [&](size_t bytes) { void* p = ws + off; off += (bytes + 255) & ~(size_t)255; return p; };
  unsigned short* WqkvT = (unsigned short*)alloc(3072ull * 1024 * 2);
  unsigned short* WoT   = (unsigned short*)alloc(1024ull * 1024 * 2);
  unsigned short* W1T   = (unsigned short*)alloc(4096ull * 1024 * 2);
  unsigned short* W2T   = (unsigned short*)alloc(1024ull * 4096 * 2);
  float* y1             = (float*)alloc(8192ull * 1024 * 4);
  // aliased activation region (80MB): [x2 16][qb 16][kb 16][vtb 16][attn_o 16]
  char* region = (char*)alloc(5ull * 16 * 1024 * 1024);
  unsigned short* x2     = (unsigned short*)(region);
  unsigned short* qb     = (unsigned short*)(region + 16ull * 1024 * 1024);
  unsigned short* kb     = (unsigned short*)(region + 32ull * 1024 * 1024);
  unsigned short* vtb    = (unsigned short*)(region + 48ull * 1024 * 1024);
  unsigned short* attn_o = (unsigned short*)(region + 64ull * 1024 * 1024);
  unsigned short* h2     = (unsigned short*)(region);                        // alias x2 (dead)
  unsigned short* ffn1   = (unsigned short*)(region + 16ull * 1024 * 1024);  // alias qb..attn_o (dead)

  transpose_cvt<<<dim3(32, 32), 256, 0, stream>>>(Wq, WqkvT, 1024, 1024);
  transpose_cvt<<<dim3(32, 32), 256, 0, stream>>>(Wk, WqkvT + 1024ull * 1024, 1024, 1024);
  transpose_cvt<<<dim3(32, 32), 256, 0, stream>>>(Wv, WqkvT + 2048ull * 1024, 1024, 1024);
  transpose_cvt<<<dim3(32, 32), 256, 0, stream>>>(Wo, WoT, 1024, 1024);
  transpose_cvt<<<dim3(128, 32), 256, 0, stream>>>(W1, W1T, 1024, 4096);
  transpose_cvt<<<dim3(32, 128), 256, 0, stream>>>(W2, W2T, 4096, 1024);

  ln_kernel<<<8192, 256, 0, stream>>>(x, g1, be1, x2, 1);

  gemm_bt<MODE_QKV><<<dim3(3072 / BN, 8192 / BM), 256, 0, stream>>>(
      x2, WqkvT, 8192, 3072, 1024, bq, bk, bv, qb, kb, vtb, nullptr, nullptr, nullptr);

  attn_kernel<<<dim3(S_LEN / 16, NHEAD, BATCH), 64, 0, stream>>>(
      qb, kb, vtb, attn_bias, kpm, alpha, attn_o);

  gemm_bt<MODE_OPROJ><<<dim3(1024 / BN, 8192 / BM), 256, 0, stream>>>(
      attn_o, WoT, 8192, 1024, 1024, bo, nullptr, nullptr,
      nullptr, nullptr, nullptr, x, y1, nullptr);

  ln_kernel<<<8192, 256, 0, stream>>>(y1, g2, be2, h2, 0);

  gemm_bt<MODE_FFN1><<<dim3(4096 / BN, 8192 / BM), 256, 0, stream>>>(
      h2, W1T, 8192, 4096, 1024, b1, nullptr, nullptr,
      nullptr, nullptr, nullptr, nullptr, nullptr, ffn1);

  gemm_bt<MODE_FFN2><<<dim3(1024 / BN, 8192 / BM), 256, 0, stream>>>(
      ffn1, W2T, 8192, 1024, 4096, b2, nullptr, nullptr,
      nullptr, nullptr, nullptr, y1, out, nullptr);
}

// Round 2
// 701.044 us; speedup vs baseline: 1.0375x; 1.0375x over previous
//
#include <hip/hip_runtime.h>
#include <stdint.h>

#define S_LEN 1024
#define BATCH 8
#define DMODEL 1024
#define NHEAD 16
#define DHEAD 64
#define DFF_N 4096
#define EPS 1e-5f

typedef __attribute__((ext_vector_type(8))) short bf16x8;
typedef __attribute__((ext_vector_type(4))) float f32x4;

__device__ __forceinline__ unsigned short f2bf(float f) {
  union { float f; unsigned u; } x; x.f = f;
  unsigned r = x.u + 0x7FFFu + ((x.u >> 16) & 1u);
  return (unsigned short)(r >> 16);
}

__device__ __forceinline__ void gld_lds16(const void* g, void* l) {
  __builtin_amdgcn_global_load_lds(
      (const __attribute__((address_space(1))) void*)g,
      (__attribute__((address_space(3))) void*)l, 16, 0, 0);
}

// ---------------- weight transpose + fp32->bf16 ----------------
// src (K,N) fp32 row-major  ->  dst (N,K) bf16 row-major
__global__ __launch_bounds__(256) void transpose_cvt(
    const float* __restrict__ src, unsigned short* __restrict__ dst, int K, int N) {
  __shared__ float tile[32][33];
  int n0 = blockIdx.x * 32, k0 = blockIdx.y * 32;
  int tx = threadIdx.x & 31, ty = threadIdx.x >> 5;  // ty 0..7
#pragma unroll
  for (int p = 0; p < 4; ++p)
    tile[ty + p * 8][tx] = src[(long)(k0 + ty + p * 8) * N + n0 + tx];
  __syncthreads();
#pragma unroll
  for (int p = 0; p < 4; ++p)
    dst[(long)(n0 + ty + p * 8) * K + k0 + tx] = f2bf(tile[tx][ty + p * 8]);
}

// ---------------- combined mask+bias precompute ----------------
__global__ __launch_bounds__(256) void biasm_kernel(
    const float* __restrict__ bias, const int* __restrict__ kpm,
    const float* __restrict__ alpha_p, float* __restrict__ biasm) {
  int i = blockIdx.x * 256 + threadIdx.x;  // B*S = 8192
  float a = alpha_p[0];
  biasm[i] = kpm[i] ? -1e30f : bias[i] * a;
}

// ---------------- LayerNorm (row = 1024), fp32 in -> bf16 out ----------------
__global__ __launch_bounds__(256) void ln_kernel(
    const float* __restrict__ in, const float* __restrict__ g,
    const float* __restrict__ be, unsigned short* __restrict__ out, int permute) {
  int rr = blockIdx.x;
  long in_off;
  if (permute) { int b = rr >> 10, s = rr & 1023; in_off = ((long)s * BATCH + b) * DMODEL; }
  else in_off = (long)rr * DMODEL;
  int t = threadIdx.x;
  float4 v = *(const float4*)(in + in_off + t * 4);
  float sum = v.x + v.y + v.z + v.w;
#pragma unroll
  for (int m = 1; m < 64; m <<= 1) sum += __shfl_xor(sum, m);
  __shared__ float red[4];
  __shared__ float red2[4];
  int wave = t >> 6, lane = t & 63;
  if (lane == 0) red[wave] = sum;
  __syncthreads();
  sum = red[0] + red[1] + red[2] + red[3];
  float mean = sum * (1.0f / DMODEL);
  float dx = v.x - mean, dy = v.y - mean, dz = v.z - mean, dw = v.w - mean;
  float vs = dx * dx + dy * dy + dz * dz + dw * dw;
#pragma unroll
  for (int m = 1; m < 64; m <<= 1) vs += __shfl_xor(vs, m);
  if (lane == 0) red2[wave] = vs;
  __syncthreads();
  vs = red2[0] + red2[1] + red2[2] + red2[3];
  float rstd = rsqrtf(vs * (1.0f / DMODEL) + EPS);
  float4 gv = *(const float4*)(g + t * 4);
  float4 bv = *(const float4*)(be + t * 4);
  ushort4 pk;
  pk.x = f2bf(dx * rstd * gv.x + bv.x);
  pk.y = f2bf(dy * rstd * gv.y + bv.y);
  pk.z = f2bf(dz * rstd * gv.z + bv.z);
  pk.w = f2bf(dw * rstd * gv.w + bv.w);
  *(ushort4*)(out + (long)rr * DMODEL + t * 4) = pk;
}

// ---------------- GEMM C = A(M,K) @ Bt(N,K)^T, bf16 in, fp32 acc ----------------
#define BM 128
#define BN 128
#define BK 64
#define MODE_QKV 0
#define MODE_OPROJ 1
#define MODE_FFN1 2
#define MODE_FFN2 3

template <int MODE>
__global__ __launch_bounds__(256) void gemm_bt(
    const unsigned short* __restrict__ A, const unsigned short* __restrict__ Bt,
    int M, int N, int K,
    const float* __restrict__ bias0, const float* __restrict__ bias1,
    const float* __restrict__ bias2,
    unsigned short* out_q, unsigned short* out_k, unsigned short* out_vt,
    const float* __restrict__ resid, float* out_f32, unsigned short* out_bf16) {
  __shared__ unsigned short As[BM * BK];
  __shared__ unsigned short Bs[BN * BK];
  int m0 = blockIdx.y * BM, n0 = blockIdx.x * BN;
  int t = threadIdx.x, wave = t >> 6, lane = t & 63;
  int wr = wave >> 1, wc = wave & 1;
  const unsigned short* Ab = A + (long)m0 * K;
  const unsigned short* Bb = Bt + (long)n0 * K;
  f32x4 acc[4][4];
#pragma unroll
  for (int i = 0; i < 4; ++i)
#pragma unroll
    for (int j = 0; j < 4; ++j) acc[i][j] = (f32x4){0.f, 0.f, 0.f, 0.f};

  int lrow = lane >> 3;        // 0..7
  int lcol = (lane & 7) * 8;   // bf16 col base

  auto stage = [&](int kt) {
    long kofs = (long)kt * BK;
#pragma unroll
    for (int j = 0; j < 4; ++j) {
      int rowbase = (j * 4 + wave) * 8;
      gld_lds16(Ab + (long)(rowbase + lrow) * K + kofs + lcol, &As[rowbase * BK]);
      gld_lds16(Bb + (long)(rowbase + lrow) * K + kofs + lcol, &Bs[rowbase * BK]);
    }
  };

  int kt_count = K / BK;
  stage(0);
  for (int kt = 0; kt < kt_count; ++kt) {
    __syncthreads();  // staged tile visible
#pragma unroll
    for (int kk = 0; kk < 2; ++kk) {
      int ko = kk * 32 + 8 * (lane >> 4);
      bf16x8 a[4], b[4];
#pragma unroll
      for (int i = 0; i < 4; ++i)
        a[i] = *(const bf16x8*)&As[(wr * 64 + i * 16 + (lane & 15)) * BK + ko];
#pragma unroll
      for (int j = 0; j < 4; ++j)
        b[j] = *(const bf16x8*)&Bs[(wc * 64 + j * 16 + (lane & 15)) * BK + ko];
#pragma unroll
      for (int i = 0; i < 4; ++i)
#pragma unroll
        for (int j = 0; j < 4; ++j)
          acc[i][j] = __builtin_amdgcn_mfma_f32_16x16x32_bf16(a[i], b[j], acc[i][j], 0, 0, 0);
    }
    __syncthreads();  // all waves done reading before restage
    if (kt + 1 < kt_count) stage(kt + 1);
  }

  // epilogue: C row = (lane>>4)*4+r, col = lane&15 per 16x16 tile
  int rbase = (lane >> 4) << 2;
#pragma unroll
  for (int i = 0; i < 4; ++i) {
#pragma unroll
    for (int j = 0; j < 4; ++j) {
      int mrow = m0 + wr * 64 + i * 16 + rbase;
      int ncol = n0 + wc * 64 + j * 16 + (lane & 15);
      if constexpr (MODE == MODE_QKV) {
        int sel = ncol >> 10, nn = ncol & 1023;
        int h = nn >> 6, dh = nn & 63;
        const float* bptr = (sel == 0) ? bias0 : ((sel == 1) ? bias1 : bias2);
        float bias = bptr[nn];
        if (sel < 2) {
          unsigned short* dst = (sel == 0) ? out_q : out_k;
#pragma unroll
          for (int r = 0; r < 4; ++r) {
            int m = mrow + r; int bb = m >> 10, s = m & 1023;
            dst[(((long)(bb * NHEAD + h)) * S_LEN + s) * DHEAD + dh] = f2bf(acc[i][j][r] + bias);
          }
        } else {
          int m = mrow; int bb = m >> 10, s = m & 1023;
          ushort4 pk;
          pk.x = f2bf(acc[i][j][0] + bias);
          pk.y = f2bf(acc[i][j][1] + bias);
          pk.z = f2bf(acc[i][j][2] + bias);
          pk.w = f2bf(acc[i][j][3] + bias);
          *(ushort4*)&out_vt[(((long)(bb * NHEAD + h)) * DHEAD + dh) * S_LEN + s] = pk;
        }
      } else if constexpr (MODE == MODE_OPROJ) {
        float bias = bias0[ncol];
#pragma unroll
        for (int r = 0; r < 4; ++r) {
          int m = mrow + r; int bb = m >> 10, s = m & 1023;
          long oi = ((long)s * BATCH + bb) * DMODEL + ncol;
          out_f32[oi] = resid[oi] + acc[i][j][r] + bias;
        }
      } else if constexpr (MODE == MODE_FFN1) {
        float bias = bias0[ncol];
#pragma unroll
        for (int r = 0; r < 4; ++r) {
          long m = mrow + r;
          float v = acc[i][j][r] + bias;
          out_bf16[m * (long)N + ncol] = f2bf(v > 0.f ? v : 0.f);
        }
      } else {  // MODE_FFN2
        float bias = bias0[ncol];
#pragma unroll
        for (int r = 0; r < 4; ++r) {
          long m = mrow + r;
          long oi = m * (long)N + ncol;
          out_f32[oi] = resid[oi] + acc[i][j][r] + bias;
        }
      }
    }
  }
}

// ---------------- flash attention, swapped-QK^T, 32 q-rows/wave ----------------
// 4 independent waves per block; wave w handles q-rows [blockIdx.x*128 + w*32, +32)
// of one (b,h). Swapped QK^T: sacc = mfma(K_frag, Q_frag) -> C[key][query], so
// each lane owns all keys of ONE query -> softmax reduce = in-reg + 2 shfl_xor.
__global__ __launch_bounds__(256) void attn_kernel(
    const unsigned short* __restrict__ qbuf, const unsigned short* __restrict__ kbuf,
    const unsigned short* __restrict__ vtbuf, const float* __restrict__ biasm,
    unsigned short* __restrict__ out) {
  int wave = threadIdx.x >> 6, lane = threadIdx.x & 63;
  int h = blockIdx.y, b = blockIdx.z;
  int q0 = blockIdx.x * 128 + wave * 32;
  long bh = (long)(b * NHEAD + h);
  const unsigned short* Q = qbuf + bh * S_LEN * DHEAD;
  const unsigned short* Kp = kbuf + bh * S_LEN * DHEAD;
  const unsigned short* Vt = vtbuf + bh * DHEAD * S_LEN;
  const float* bm = biasm + (long)b * S_LEN;

  // per-wave private P tile: [frag 2][16 q-rows][16 uint2 (=64 keys bf16)]
  __shared__ uint2 Pbuf[4][512];
  __shared__ float AL[4][2][16];
  __shared__ float LI[4][2][16];
  uint2* Pw = Pbuf[wave];

  int qr = lane & 15, g = lane >> 4;

  bf16x8 qf[2][2];
#pragma unroll
  for (int f = 0; f < 2; ++f)
#pragma unroll
    for (int dhh = 0; dhh < 2; ++dhh)
      qf[f][dhh] = *(const bf16x8*)&Q[(long)(q0 + f * 16 + qr) * DHEAD + dhh * 32 + g * 8];

  f32x4 oacc[2][4];
#pragma unroll
  for (int f = 0; f < 2; ++f)
#pragma unroll
    for (int dt = 0; dt < 4; ++dt) oacc[f][dt] = (f32x4){0.f, 0.f, 0.f, 0.f};
  float m_[2] = {-1e30f, -1e30f}, l_[2] = {0.f, 0.f};

  for (int k0 = 0; k0 < S_LEN; k0 += 64) {
    f32x4 sacc[2][4];
#pragma unroll
    for (int f = 0; f < 2; ++f)
#pragma unroll
      for (int n = 0; n < 4; ++n) sacc[f][n] = (f32x4){0.f, 0.f, 0.f, 0.f};
#pragma unroll
    for (int n = 0; n < 4; ++n) {
#pragma unroll
      for (int dhh = 0; dhh < 2; ++dhh) {
        bf16x8 kf = *(const bf16x8*)&Kp[(long)(k0 + n * 16 + qr) * DHEAD + dhh * 32 + g * 8];
        sacc[0][n] = __builtin_amdgcn_mfma_f32_16x16x32_bf16(kf, qf[0][dhh], sacc[0][n], 0, 0, 0);
        sacc[1][n] = __builtin_amdgcn_mfma_f32_16x16x32_bf16(kf, qf[1][dhh], sacc[1][n], 0, 0, 0);
      }
    }
    float4 bv[4];
#pragma unroll
    for (int n = 0; n < 4; ++n) bv[n] = *(const float4*)&bm[k0 + n * 16 + g * 4];

#pragma unroll
    for (int f = 0; f < 2; ++f) {
      float s[16];
#pragma unroll
      for (int n = 0; n < 4; ++n) {
        const float* bvp = (const float*)&bv[n];
#pragma unroll
        for (int r = 0; r < 4; ++r) s[n * 4 + r] = fmaf(sacc[f][n][r], 0.125f, bvp[r]);
      }
      float mx = s[0];
#pragma unroll
      for (int i = 1; i < 16; ++i) mx = fmaxf(mx, s[i]);
      mx = fmaxf(mx, __shfl_xor(mx, 16));
      mx = fmaxf(mx, __shfl_xor(mx, 32));
      float mnew = fmaxf(m_[f], mx);
      float al = __expf(m_[f] - mnew);
      m_[f] = mnew;
      float ps = 0.f;
#pragma unroll
      for (int i = 0; i < 16; ++i) { s[i] = __expf(s[i] - mnew); ps += s[i]; }
      ps += __shfl_xor(ps, 16);
      ps += __shfl_xor(ps, 32);
      l_[f] = l_[f] * al + ps;
      if (lane < 16) AL[wave][f][lane] = al;
      // pack P to bf16, write swizzled: uint2 index-in-row = (4n+g) ^ qr
#pragma unroll
      for (int n = 0; n < 4; ++n) {
        unsigned w0, w1;
        asm("v_cvt_pk_bf16_f32 %0, %1, %2" : "=v"(w0) : "v"(s[n * 4 + 0]), "v"(s[n * 4 + 1]));
        asm("v_cvt_pk_bf16_f32 %0, %1, %2" : "=v"(w1) : "v"(s[n * 4 + 2]), "v"(s[n * 4 + 3]));
        Pw[(f * 16 + qr) * 16 + ((n * 4 + g) ^ qr)] = (uint2){w0, w1};
      }
    }
    // rescale oacc by al (per-query, broadcast via LDS float4)
#pragma unroll
    for (int f = 0; f < 2; ++f) {
      float4 alv = *(const float4*)&AL[wave][f][g * 4];
      const float* ap = (const float*)&alv;
#pragma unroll
      for (int dt = 0; dt < 4; ++dt)
#pragma unroll
        for (int r = 0; r < 4; ++r) oacc[f][dt][r] *= ap[r];
    }
    // PV: A-frag = P rows (queries), k = keys; B-frag = Vt rows (dh)
#pragma unroll
    for (int kb = 0; kb < 2; ++kb) {
      union { uint2 u[2]; bf16x8 v; } p0, p1;
      p0.u[0] = Pw[(0 * 16 + qr) * 16 + ((kb * 8 + g * 2 + 0) ^ qr)];
      p0.u[1] = Pw[(0 * 16 + qr) * 16 + ((kb * 8 + g * 2 + 1) ^ qr)];
      p1.u[0] = Pw[(1 * 16 + qr) * 16 + ((kb * 8 + g * 2 + 0) ^ qr)];
      p1.u[1] = Pw[(1 * 16 + qr) * 16 + ((kb * 8 + g * 2 + 1) ^ qr)];
#pragma unroll
      for (int dt = 0; dt < 4; ++dt) {
        bf16x8 vf = *(const bf16x8*)&Vt[(long)(dt * 16 + qr) * S_LEN + k0 + kb * 32 + g * 8];
        oacc[0][dt] = __builtin_amdgcn_mfma_f32_16x16x32_bf16(p0.v, vf, oacc[0][dt], 0, 0, 0);
        oacc[1][dt] = __builtin_amdgcn_mfma_f32_16x16x32_bf16(p1.v, vf, oacc[1][dt], 0, 0, 0);
      }
    }
  }

#pragma unroll
  for (int f = 0; f < 2; ++f)
    if (lane < 16) LI[wave][f][lane] = 1.0f / l_[f];
#pragma unroll
  for (int f = 0; f < 2; ++f) {
    float4 lv = *(const float4*)&LI[wave][f][g * 4];
    const float* lp = (const float*)&lv;
#pragma unroll
    for (int dt = 0; dt < 4; ++dt)
#pragma unroll
      for (int r = 0; r < 4; ++r) {
        int q = q0 + f * 16 + g * 4 + r;
        int dh = dt * 16 + qr;
        out[((long)(b * S_LEN + q)) * DMODEL + h * DHEAD + dh] = f2bf(oacc[f][dt][r] * lp[r]);
      }
  }
}

// ---------------- host launcher ----------------
extern "C" void kernel_launch(void* const* d_in, const int* in_sizes, int n_in,
                              void* d_out, int out_size, void* d_ws, size_t ws_size,
                              hipStream_t stream) {
  const float* x  = (const float*)d_in[0];
  const int* kpm  = (const int*)d_in[1];
  const float* attn_bias = (const float*)d_in[2];
  const float* Wq = (const float*)d_in[3];  const float* bq = (const float*)d_in[4];
  const float* Wk = (const float*)d_in[5];  const float* bk = (const float*)d_in[6];
  const float* Wv = (const float*)d_in[7];  const float* bv = (const float*)d_in[8];
  const float* Wo = (const float*)d_in[9];  const float* bo = (const float*)d_in[10];
  const float* W1 = (const float*)d_in[11]; const float* b1 = (const float*)d_in[12];
  const float* W2 = (const float*)d_in[13]; const float* b2 = (const float*)d_in[14];
  const float* g1 = (const float*)d_in[15]; const float* be1 = (const float*)d_in[16];
  const float* g2 = (const float*)d_in[17]; const float* be2 = (const float*)d_in[18];
  const float* alpha = (const float*)d_in[19];
  float* out = (float*)d_out;

  char* ws = (char*)d_ws;
  size_t off = 0;
  auto alloc = [&](size_t bytes) { void* p = ws + off; off += (bytes + 255) & ~(size_t)255; return p; };
  unsigned short* WqkvT = (unsigned short*)alloc(3072ull * 1024 * 2);
  unsigned short* WoT   = (unsigned short*)alloc(1024ull * 1024 * 2);
  unsigned short* W1T   = (unsigned short*)alloc(4096ull * 1024 * 2);
  unsigned short* W2T   = (unsigned short*)alloc(1024ull * 4096 * 2);
  float* biasm          = (float*)alloc(8192ull * 4);
  float* y1             = (float*)alloc(8192ull * 1024 * 4);
  // aliased activation region (80MB): [x2 16][qb 16][kb 16][vtb 16][attn_o 16]
  char* region = (char*)alloc(5ull * 16 * 1024 * 1024);
  unsigned short* x2     = (unsigned short*)(region);
  unsigned short* qb     = (unsigned short*)(region + 16ull * 1024 * 1024);
  unsigned short* kb     = (unsigned short*)(region + 32ull * 1024 * 1024);
  unsigned short* vtb    = (unsigned short*)(region + 48ull * 1024 * 1024);
  unsigned short* attn_o = (unsigned short*)(region + 64ull * 1024 * 1024);
  unsigned short* h2     = (unsigned short*)(region);                        // alias x2 (dead)
  unsigned short* ffn1   = (unsigned short*)(region + 16ull * 1024 * 1024);  // alias qb..attn_o (dead)

  transpose_cvt<<<dim3(32, 32), 256, 0, stream>>>(Wq, WqkvT, 1024, 1024);
  transpose_cvt<<<dim3(32, 32), 256, 0, stream>>>(Wk, WqkvT + 1024ull * 1024, 1024, 1024);
  transpose_cvt<<<dim3(32, 32), 256, 0, stream>>>(Wv, WqkvT + 2048ull * 1024, 1024, 1024);
  transpose_cvt<<<dim3(32, 32), 256, 0, stream>>>(Wo, WoT, 1024, 1024);
  transpose_cvt<<<dim3(128, 32), 256, 0, stream>>>(W1, W1T, 1024, 4096);
  transpose_cvt<<<dim3(32, 128), 256, 0, stream>>>(W2, W2T, 4096, 1024);

  biasm_kernel<<<32, 256, 0, stream>>>(attn_bias, kpm, alpha, biasm);
  ln_kernel<<<8192, 256, 0, stream>>>(x, g1, be1, x2, 1);

  gemm_bt<MODE_QKV><<<dim3(3072 / BN, 8192 / BM), 256, 0, stream>>>(
      x2, WqkvT, 8192, 3072, 1024, bq, bk, bv, qb, kb, vtb, nullptr, nullptr, nullptr);

  attn_kernel<<<dim3(S_LEN / 128, NHEAD, BATCH), 256, 0, stream>>>(
      qb, kb, vtb, biasm, attn_o);

  gemm_bt<MODE_OPROJ><<<dim3(1024 / BN, 8192 / BM), 256, 0, stream>>>(
      attn_o, WoT, 8192, 1024, 1024, bo, nullptr, nullptr,
      nullptr, nullptr, nullptr, x, y1, nullptr);

  ln_kernel<<<8192, 256, 0, stream>>>(y1, g2, be2, h2, 0);

  gemm_bt<MODE_FFN1><<<dim3(4096 / BN, 8192 / BM), 256, 0, stream>>>(
      h2, W1T, 8192, 4096, 1024, b1, nullptr, nullptr,
      nullptr, nullptr, nullptr, nullptr, nullptr, ffn1);

  gemm_bt<MODE_FFN2><<<dim3(1024 / BN, 8192 / BM), 256, 0, stream>>>(
      ffn1, W2T, 8192, 1024, 4096, b2, nullptr, nullptr,
      nullptr, nullptr, nullptr, y1, out, nullptr);
}

// Round 3
// 568.007 us; speedup vs baseline: 1.2805x; 1.2342x over previous
//
#include <hip/hip_runtime.h>
#include <stdint.h>

#define S_LEN 1024
#define BATCH 8
#define DMODEL 1024
#define NHEAD 16
#define DHEAD 64
#define DFF_N 4096
#define EPS 1e-5f

typedef __attribute__((ext_vector_type(8))) short bf16x8;
typedef __attribute__((ext_vector_type(4))) float f32x4;

__device__ __forceinline__ unsigned short f2bf(float f) {
  union { float f; unsigned u; } x; x.f = f;
  unsigned r = x.u + 0x7FFFu + ((x.u >> 16) & 1u);
  return (unsigned short)(r >> 16);
}

__device__ __forceinline__ void gld_lds16(const void* g, void* l) {
  __builtin_amdgcn_global_load_lds(
      (const __attribute__((address_space(1))) void*)g,
      (__attribute__((address_space(3))) void*)l, 16, 0, 0);
}

// ---------------- weight transpose + fp32->bf16 ----------------
__global__ __launch_bounds__(256) void transpose_cvt(
    const float* __restrict__ src, unsigned short* __restrict__ dst, int K, int N) {
  __shared__ float tile[32][33];
  int n0 = blockIdx.x * 32, k0 = blockIdx.y * 32;
  int tx = threadIdx.x & 31, ty = threadIdx.x >> 5;
#pragma unroll
  for (int p = 0; p < 4; ++p)
    tile[ty + p * 8][tx] = src[(long)(k0 + ty + p * 8) * N + n0 + tx];
  __syncthreads();
#pragma unroll
  for (int p = 0; p < 4; ++p)
    dst[(long)(n0 + ty + p * 8) * K + k0 + tx] = f2bf(tile[tx][ty + p * 8]);
}

// ---------------- combined mask+bias precompute ----------------
__global__ __launch_bounds__(256) void biasm_kernel(
    const float* __restrict__ bias, const int* __restrict__ kpm,
    const float* __restrict__ alpha_p, float* __restrict__ biasm) {
  int i = blockIdx.x * 256 + threadIdx.x;  // B*S = 8192
  float a = alpha_p[0];
  biasm[i] = kpm[i] ? -1e30f : bias[i] * a;
}

// ---------------- LayerNorm (row = 1024), fp32 in -> bf16 out ----------------
__global__ __launch_bounds__(256) void ln_kernel(
    const float* __restrict__ in, const float* __restrict__ g,
    const float* __restrict__ be, unsigned short* __restrict__ out, int permute) {
  int rr = blockIdx.x;
  long in_off;
  if (permute) { int b = rr >> 10, s = rr & 1023; in_off = ((long)s * BATCH + b) * DMODEL; }
  else in_off = (long)rr * DMODEL;
  int t = threadIdx.x;
  float4 v = *(const float4*)(in + in_off + t * 4);
  float sum = v.x + v.y + v.z + v.w;
#pragma unroll
  for (int m = 1; m < 64; m <<= 1) sum += __shfl_xor(sum, m);
  __shared__ float red[4];
  __shared__ float red2[4];
  int wave = t >> 6, lane = t & 63;
  if (lane == 0) red[wave] = sum;
  __syncthreads();
  sum = red[0] + red[1] + red[2] + red[3];
  float mean = sum * (1.0f / DMODEL);
  float dx = v.x - mean, dy = v.y - mean, dz = v.z - mean, dw = v.w - mean;
  float vs = dx * dx + dy * dy + dz * dz + dw * dw;
#pragma unroll
  for (int m = 1; m < 64; m <<= 1) vs += __shfl_xor(vs, m);
  if (lane == 0) red2[wave] = vs;
  __syncthreads();
  vs = red2[0] + red2[1] + red2[2] + red2[3];
  float rstd = rsqrtf(vs * (1.0f / DMODEL) + EPS);
  float4 gv = *(const float4*)(g + t * 4);
  float4 bv = *(const float4*)(be + t * 4);
  ushort4 pk;
  pk.x = f2bf(dx * rstd * gv.x + bv.x);
  pk.y = f2bf(dy * rstd * gv.y + bv.y);
  pk.z = f2bf(dz * rstd * gv.z + bv.z);
  pk.w = f2bf(dw * rstd * gv.w + bv.w);
  *(ushort4*)(out + (long)rr * DMODEL + t * 4) = pk;
}

// ---------------- GEMM C = A(M,K) @ Bt(N,K)^T, bf16 in, fp32 acc ----------------
#define BM 128
#define BN 128
#define BK 64
#define MODE_QKV 0
#define MODE_OPROJ 1
#define MODE_FFN1 2
#define MODE_FFN2 3

template <int MODE>
__global__ __launch_bounds__(256) void gemm_bt(
    const unsigned short* __restrict__ A, const unsigned short* __restrict__ Bt,
    int M, int N, int K,
    const float* __restrict__ bias0, const float* __restrict__ bias1,
    const float* __restrict__ bias2,
    unsigned short* out_q, unsigned short* out_k, unsigned short* out_vt,
    const float* __restrict__ resid, float* out_f32, unsigned short* out_bf16) {
  __shared__ unsigned short As[BM * BK];
  __shared__ unsigned short Bs[BN * BK];
  // bijective XCD-aware swizzle (all grids have nwg % 8 == 0)
  int nbx = gridDim.x;
  int nwg = nbx * gridDim.y;
  int orig = blockIdx.y * nbx + blockIdx.x;
  int cpx = nwg >> 3;
  int swz = (orig & 7) * cpx + (orig >> 3);
  int bx = swz % nbx, by = swz / nbx;
  int m0 = by * BM, n0 = bx * BN;
  int t = threadIdx.x, wave = t >> 6, lane = t & 63;
  int wr = wave >> 1, wc = wave & 1;
  const unsigned short* Ab = A + (long)m0 * K;
  const unsigned short* Bb = Bt + (long)n0 * K;
  f32x4 acc[4][4];
#pragma unroll
  for (int i = 0; i < 4; ++i)
#pragma unroll
    for (int j = 0; j < 4; ++j) acc[i][j] = (f32x4){0.f, 0.f, 0.f, 0.f};

  int lrow = lane >> 3;        // 0..7
  int lcol = (lane & 7) * 8;   // bf16 col base

  auto stage = [&](int kt) {
    long kofs = (long)kt * BK;
#pragma unroll
    for (int j = 0; j < 4; ++j) {
      int rowbase = (j * 4 + wave) * 8;
      gld_lds16(Ab + (long)(rowbase + lrow) * K + kofs + lcol, &As[rowbase * BK]);
      gld_lds16(Bb + (long)(rowbase + lrow) * K + kofs + lcol, &Bs[rowbase * BK]);
    }
  };

  int kt_count = K / BK;
  stage(0);
  for (int kt = 0; kt < kt_count; ++kt) {
    __syncthreads();
#pragma unroll
    for (int kk = 0; kk < 2; ++kk) {
      int ko = kk * 32 + 8 * (lane >> 4);
      bf16x8 a[4], b[4];
#pragma unroll
      for (int i = 0; i < 4; ++i)
        a[i] = *(const bf16x8*)&As[(wr * 64 + i * 16 + (lane & 15)) * BK + ko];
#pragma unroll
      for (int j = 0; j < 4; ++j)
        b[j] = *(const bf16x8*)&Bs[(wc * 64 + j * 16 + (lane & 15)) * BK + ko];
#pragma unroll
      for (int i = 0; i < 4; ++i)
#pragma unroll
        for (int j = 0; j < 4; ++j)
          acc[i][j] = __builtin_amdgcn_mfma_f32_16x16x32_bf16(a[i], b[j], acc[i][j], 0, 0, 0);
    }
    __syncthreads();
    if (kt + 1 < kt_count) stage(kt + 1);
  }

  int rbase = (lane >> 4) << 2;
#pragma unroll
  for (int i = 0; i < 4; ++i) {
#pragma unroll
    for (int j = 0; j < 4; ++j) {
      int mrow = m0 + wr * 64 + i * 16 + rbase;
      int ncol = n0 + wc * 64 + j * 16 + (lane & 15);
      if constexpr (MODE == MODE_QKV) {
        int sel = ncol >> 10, nn = ncol & 1023;
        int h = nn >> 6, dh = nn & 63;
        const float* bptr = (sel == 0) ? bias0 : ((sel == 1) ? bias1 : bias2);
        float bias = bptr[nn];
        if (sel < 2) {
          unsigned short* dst = (sel == 0) ? out_q : out_k;
#pragma unroll
          for (int r = 0; r < 4; ++r) {
            int m = mrow + r; int bb = m >> 10, s = m & 1023;
            dst[(((long)(bb * NHEAD + h)) * S_LEN + s) * DHEAD + dh] = f2bf(acc[i][j][r] + bias);
          }
        } else {
          int m = mrow; int bb = m >> 10, s = m & 1023;
          ushort4 pk;
          pk.x = f2bf(acc[i][j][0] + bias);
          pk.y = f2bf(acc[i][j][1] + bias);
          pk.z = f2bf(acc[i][j][2] + bias);
          pk.w = f2bf(acc[i][j][3] + bias);
          *(ushort4*)&out_vt[(((long)(bb * NHEAD + h)) * DHEAD + dh) * S_LEN + s] = pk;
        }
      } else if constexpr (MODE == MODE_OPROJ) {
        float bias = bias0[ncol];
#pragma unroll
        for (int r = 0; r < 4; ++r) {
          int m = mrow + r; int bb = m >> 10, s = m & 1023;
          long oi = ((long)s * BATCH + bb) * DMODEL + ncol;
          out_f32[oi] = resid[oi] + acc[i][j][r] + bias;
        }
      } else if constexpr (MODE == MODE_FFN1) {
        float bias = bias0[ncol];
#pragma unroll
        for (int r = 0; r < 4; ++r) {
          long m = mrow + r;
          float v = acc[i][j][r] + bias;
          out_bf16[m * (long)N + ncol] = f2bf(v > 0.f ? v : 0.f);
        }
      } else {  // MODE_FFN2
        float bias = bias0[ncol];
#pragma unroll
        for (int r = 0; r < 4; ++r) {
          long m = mrow + r;
          long oi = m * (long)N + ncol;
          out_f32[oi] = resid[oi] + acc[i][j][r] + bias;
        }
      }
    }
  }
}

// ---------------- flash attention v3: 8 waves/block, LDS-staged K/V ----------------
// Block = 512 thr = 8 waves, each wave 32 q-rows -> block covers 256 q-rows of one
// (b,h). K/V tiles (64 keys) double-buffered in LDS via global_load_lds with
// both-sides XOR swizzle (chunk ^= row&7). Swapped QK^T (mfma(K,Q)) keeps softmax
// per-lane; P redistributed through per-wave swizzled LDS tile.
__global__ __launch_bounds__(512, 4) void attn_kernel(
    const unsigned short* __restrict__ qbuf, const unsigned short* __restrict__ kbuf,
    const unsigned short* __restrict__ vtbuf, const float* __restrict__ biasm,
    unsigned short* __restrict__ out) {
  int wave = threadIdx.x >> 6, lane = threadIdx.x & 63;
  int h = blockIdx.y, b = blockIdx.z;
  int q0 = blockIdx.x * 256 + wave * 32;
  long bh = (long)(b * NHEAD + h);
  const unsigned short* Q = qbuf + bh * S_LEN * DHEAD;
  const unsigned short* Kp = kbuf + bh * S_LEN * DHEAD;
  const unsigned short* Vt = vtbuf + bh * DHEAD * S_LEN;
  const float* bm = biasm + (long)b * S_LEN;

  __shared__ unsigned short Ktile[2][64 * 64];  // 16 KB
  __shared__ unsigned short Vtile[2][64 * 64];  // 16 KB
  __shared__ uint2 Pbuf[8][256];                // 16 KB (per-wave 16x16 uint2)
  __shared__ float AL[8][2][16];
  __shared__ float LI[8][2][16];
  uint2* Pw = Pbuf[wave];

  int qr = lane & 15, g = lane >> 4;

  // staging source (pre-swizzled global addr; LDS dest linear at wave*1024B)
  int srow = wave * 8 + (lane >> 3);       // tile row 0..63
  int scol = (lane & 7) ^ (srow & 7);      // swizzled chunk 0..7
  const unsigned short* Ksrc = Kp + (long)srow * DHEAD + scol * 8;
  const unsigned short* Vsrc = Vt + (long)srow * S_LEN + scol * 8;

  bf16x8 qf[2][2];
#pragma unroll
  for (int f = 0; f < 2; ++f)
#pragma unroll
    for (int dhh = 0; dhh < 2; ++dhh)
      qf[f][dhh] = *(const bf16x8*)&Q[(long)(q0 + f * 16 + qr) * DHEAD + dhh * 32 + g * 8];

  f32x4 oacc[2][4];
#pragma unroll
  for (int f = 0; f < 2; ++f)
#pragma unroll
    for (int dt = 0; dt < 4; ++dt) oacc[f][dt] = (f32x4){0.f, 0.f, 0.f, 0.f};
  float m_[2] = {-1e30f, -1e30f}, l_[2] = {0.f, 0.f};

  auto stage = [&](int k0s, int buf) {
    gld_lds16(Ksrc + (long)k0s * DHEAD, (char*)&Ktile[buf][0] + wave * 1024);
    gld_lds16(Vsrc + k0s, (char*)&Vtile[buf][0] + wave * 1024);
  };

  stage(0, 0);
  int cur = 0;
  const int NT = S_LEN / 64;
  for (int t = 0; t < NT; ++t) {
    __syncthreads();  // staged buf[cur] visible; prev compute on buf[cur^1] done
    if (t + 1 < NT) stage((t + 1) * 64, cur ^ 1);

    const char* Kt_l = (const char*)&Ktile[cur][0];
    f32x4 sacc[2][4];
#pragma unroll
    for (int f = 0; f < 2; ++f)
#pragma unroll
      for (int n = 0; n < 4; ++n) sacc[f][n] = (f32x4){0.f, 0.f, 0.f, 0.f};
#pragma unroll
    for (int n = 0; n < 4; ++n)
#pragma unroll
      for (int dhh = 0; dhh < 2; ++dhh) {
        bf16x8 kf = *(const bf16x8*)(Kt_l + (n * 16 + qr) * 128 + (((dhh * 4 + g) ^ (qr & 7)) * 16));
        sacc[0][n] = __builtin_amdgcn_mfma_f32_16x16x32_bf16(kf, qf[0][dhh], sacc[0][n], 0, 0, 0);
        sacc[1][n] = __builtin_amdgcn_mfma_f32_16x16x32_bf16(kf, qf[1][dhh], sacc[1][n], 0, 0, 0);
      }
    float4 bv[4];
#pragma unroll
    for (int n = 0; n < 4; ++n) bv[n] = *(const float4*)&bm[t * 64 + n * 16 + g * 4];

    bf16x8 paf[2][2];
#pragma unroll
    for (int f = 0; f < 2; ++f) {
      float s[16];
#pragma unroll
      for (int n = 0; n < 4; ++n) {
        const float* bvp = (const float*)&bv[n];
#pragma unroll
        for (int r = 0; r < 4; ++r) s[n * 4 + r] = fmaf(sacc[f][n][r], 0.125f, bvp[r]);
      }
      float mx = s[0];
#pragma unroll
      for (int i = 1; i < 16; ++i) mx = fmaxf(mx, s[i]);
      mx = fmaxf(mx, __shfl_xor(mx, 16));
      mx = fmaxf(mx, __shfl_xor(mx, 32));
      float mnew = fmaxf(m_[f], mx);
      float al = __expf(m_[f] - mnew);
      m_[f] = mnew;
      float ps = 0.f;
#pragma unroll
      for (int i = 0; i < 16; ++i) { s[i] = __expf(s[i] - mnew); ps += s[i]; }
      ps += __shfl_xor(ps, 16);
      ps += __shfl_xor(ps, 32);
      l_[f] = l_[f] * al + ps;
      if (lane < 16) AL[wave][f][lane] = al;
#pragma unroll
      for (int n = 0; n < 4; ++n) {
        unsigned w0, w1;
        asm("v_cvt_pk_bf16_f32 %0, %1, %2" : "=v"(w0) : "v"(s[n * 4 + 0]), "v"(s[n * 4 + 1]));
        asm("v_cvt_pk_bf16_f32 %0, %1, %2" : "=v"(w1) : "v"(s[n * 4 + 2]), "v"(s[n * 4 + 3]));
        Pw[qr * 16 + ((n * 4 + g) ^ qr)] = (uint2){w0, w1};
      }
#pragma unroll
      for (int kb = 0; kb < 2; ++kb) {
        union { uint2 u[2]; bf16x8 v; } p;
        p.u[0] = Pw[qr * 16 + ((kb * 8 + g * 2 + 0) ^ qr)];
        p.u[1] = Pw[qr * 16 + ((kb * 8 + g * 2 + 1) ^ qr)];
        paf[f][kb] = p.v;
      }
    }
#pragma unroll
    for (int f = 0; f < 2; ++f) {
      float4 alv = *(const float4*)&AL[wave][f][g * 4];
      const float* ap = (const float*)&alv;
#pragma unroll
      for (int dt = 0; dt < 4; ++dt)
#pragma unroll
        for (int r = 0; r < 4; ++r) oacc[f][dt][r] *= ap[r];
    }
    const char* Vt_l = (const char*)&Vtile[cur][0];
#pragma unroll
    for (int dt = 0; dt < 4; ++dt)
#pragma unroll
      for (int kb = 0; kb < 2; ++kb) {
        bf16x8 vf = *(const bf16x8*)(Vt_l + (dt * 16 + qr) * 128 + (((kb * 4 + g) ^ (qr & 7)) * 16));
        oacc[0][dt] = __builtin_amdgcn_mfma_f32_16x16x32_bf16(paf[0][kb], vf, oacc[0][dt], 0, 0, 0);
        oacc[1][dt] = __builtin_amdgcn_mfma_f32_16x16x32_bf16(paf[1][kb], vf, oacc[1][dt], 0, 0, 0);
      }
    cur ^= 1;
  }

#pragma unroll
  for (int f = 0; f < 2; ++f)
    if (lane < 16) LI[wave][f][lane] = 1.0f / l_[f];
#pragma unroll
  for (int f = 0; f < 2; ++f) {
    float4 lv = *(const float4*)&LI[wave][f][g * 4];
    const float* lp = (const float*)&lv;
#pragma unroll
    for (int dt = 0; dt < 4; ++dt)
#pragma unroll
      for (int r = 0; r < 4; ++r) {
        int q = q0 + f * 16 + g * 4 + r;
        int dh = dt * 16 + qr;
        out[((long)(b * S_LEN + q)) * DMODEL + h * DHEAD + dh] = f2bf(oacc[f][dt][r] * lp[r]);
      }
  }
}

// ---------------- host launcher ----------------
extern "C" void kernel_launch(void* const* d_in, const int* in_sizes, int n_in,
                              void* d_out, int out_size, void* d_ws, size_t ws_size,
                              hipStream_t stream) {
  const float* x  = (const float*)d_in[0];
  const int* kpm  = (const int*)d_in[1];
  const float* attn_bias = (const float*)d_in[2];
  const float* Wq = (const float*)d_in[3];  const float* bq = (const float*)d_in[4];
  const float* Wk = (const float*)d_in[5];  const float* bk = (const float*)d_in[6];
  const float* Wv = (const float*)d_in[7];  const float* bv = (const float*)d_in[8];
  const float* Wo = (const float*)d_in[9];  const float* bo = (const float*)d_in[10];
  const float* W1 = (const float*)d_in[11]; const float* b1 = (const float*)d_in[12];
  const float* W2 = (const float*)d_in[13]; const float* b2 = (const float*)d_in[14];
  const float* g1 = (const float*)d_in[15]; const float* be1 = (const float*)d_in[16];
  const float* g2 = (const float*)d_in[17]; const float* be2 = (const float*)d_in[18];
  const float* alpha = (const float*)d_in[19];
  float* out = (float*)d_out;

  char* ws = (char*)d_ws;
  size_t off = 0;
  auto alloc = [&](size_t bytes) { void* p = ws + off; off += (bytes + 255) & ~(size_t)255; return p; };
  unsigned short* WqkvT = (unsigned short*)alloc(3072ull * 1024 * 2);
  unsigned short* WoT   = (unsigned short*)alloc(1024ull * 1024 * 2);
  unsigned short* W1T   = (unsigned short*)alloc(4096ull * 1024 * 2);
  unsigned short* W2T   = (unsigned short*)alloc(1024ull * 4096 * 2);
  float* biasm          = (float*)alloc(8192ull * 4);
  float* y1             = (float*)alloc(8192ull * 1024 * 4);
  char* region = (char*)alloc(5ull * 16 * 1024 * 1024);
  unsigned short* x2     = (unsigned short*)(region);
  unsigned short* qb     = (unsigned short*)(region + 16ull * 1024 * 1024);
  unsigned short* kb     = (unsigned short*)(region + 32ull * 1024 * 1024);
  unsigned short* vtb    = (unsigned short*)(region + 48ull * 1024 * 1024);
  unsigned short* attn_o = (unsigned short*)(region + 64ull * 1024 * 1024);
  unsigned short* h2     = (unsigned short*)(region);                        // alias x2 (dead)
  unsigned short* ffn1   = (unsigned short*)(region + 16ull * 1024 * 1024);  // alias qb.. (dead)

  transpose_cvt<<<dim3(32, 32), 256, 0, stream>>>(Wq, WqkvT, 1024, 1024);
  transpose_cvt<<<dim3(32, 32), 256, 0, stream>>>(Wk, WqkvT + 1024ull * 1024, 1024, 1024);
  transpose_cvt<<<dim3(32, 32), 256, 0, stream>>>(Wv, WqkvT + 2048ull * 1024, 1024, 1024);
  transpose_cvt<<<dim3(32, 32), 256, 0, stream>>>(Wo, WoT, 1024, 1024);
  transpose_cvt<<<dim3(128, 32), 256, 0, stream>>>(W1, W1T, 1024, 4096);
  transpose_cvt<<<dim3(32, 128), 256, 0, stream>>>(W2, W2T, 4096, 1024);

  biasm_kernel<<<32, 256, 0, stream>>>(attn_bias, kpm, alpha, biasm);
  ln_kernel<<<8192, 256, 0, stream>>>(x, g1, be1, x2, 1);

  gemm_bt<MODE_QKV><<<dim3(3072 / BN, 8192 / BM), 256, 0, stream>>>(
      x2, WqkvT, 8192, 3072, 1024, bq, bk, bv, qb, kb, vtb, nullptr, nullptr, nullptr);

  attn_kernel<<<dim3(S_LEN / 256, NHEAD, BATCH), 512, 0, stream>>>(
      qb, kb, vtb, biasm, attn_o);

  gemm_bt<MODE_OPROJ><<<dim3(1024 / BN, 8192 / BM), 256, 0, stream>>>(
      attn_o, WoT, 8192, 1024, 1024, bo, nullptr, nullptr,
      nullptr, nullptr, nullptr, x, y1, nullptr);

  ln_kernel<<<8192, 256, 0, stream>>>(y1, g2, be2, h2, 0);

  gemm_bt<MODE_FFN1><<<dim3(4096 / BN, 8192 / BM), 256, 0, stream>>>(
      h2, W1T, 8192, 4096, 1024, b1, nullptr, nullptr,
      nullptr, nullptr, nullptr, nullptr, nullptr, ffn1);

  gemm_bt<MODE_FFN2><<<dim3(1024 / BN, 8192 / BM), 256, 0, stream>>>(
      ffn1, W2T, 8192, 1024, 4096, b2, nullptr, nullptr,
      nullptr, nullptr, nullptr, y1, out, nullptr);
}

// Round 4
// 560.840 us; speedup vs baseline: 1.2968x; 1.0128x over previous
//
#include <hip/hip_runtime.h>
#include <stdint.h>

#define S_LEN 1024
#define BATCH 8
#define DMODEL 1024
#define NHEAD 16
#define DHEAD 64
#define DFF_N 4096
#define EPS 1e-5f

typedef __attribute__((ext_vector_type(8))) short bf16x8;
typedef __attribute__((ext_vector_type(4))) float f32x4;

__device__ __forceinline__ unsigned short f2bf(float f) {
  union { float f; unsigned u; } x; x.f = f;
  unsigned r = x.u + 0x7FFFu + ((x.u >> 16) & 1u);
  return (unsigned short)(r >> 16);
}

__device__ __forceinline__ void gld_lds16(const void* g, void* l) {
  __builtin_amdgcn_global_load_lds(
      (const __attribute__((address_space(1))) void*)g,
      (__attribute__((address_space(3))) void*)l, 16, 0, 0);
}

// ---------------- weight transpose + fp32->bf16 ----------------
__global__ __launch_bounds__(256) void transpose_cvt(
    const float* __restrict__ src, unsigned short* __restrict__ dst, int K, int N) {
  __shared__ float tile[32][33];
  int n0 = blockIdx.x * 32, k0 = blockIdx.y * 32;
  int tx = threadIdx.x & 31, ty = threadIdx.x >> 5;
#pragma unroll
  for (int p = 0; p < 4; ++p)
    tile[ty + p * 8][tx] = src[(long)(k0 + ty + p * 8) * N + n0 + tx];
  __syncthreads();
#pragma unroll
  for (int p = 0; p < 4; ++p)
    dst[(long)(n0 + ty + p * 8) * K + k0 + tx] = f2bf(tile[tx][ty + p * 8]);
}

// ---------------- combined mask+bias precompute ----------------
__global__ __launch_bounds__(256) void biasm_kernel(
    const float* __restrict__ bias, const int* __restrict__ kpm,
    const float* __restrict__ alpha_p, float* __restrict__ biasm) {
  int i = blockIdx.x * 256 + threadIdx.x;  // B*S = 8192
  float a = alpha_p[0];
  biasm[i] = kpm[i] ? -1e30f : bias[i] * a;
}

// ---------------- LayerNorm (row = 1024), fp32 in -> bf16 out ----------------
__global__ __launch_bounds__(256) void ln_kernel(
    const float* __restrict__ in, const float* __restrict__ g,
    const float* __restrict__ be, unsigned short* __restrict__ out, int permute) {
  int rr = blockIdx.x;
  long in_off;
  if (permute) { int b = rr >> 10, s = rr & 1023; in_off = ((long)s * BATCH + b) * DMODEL; }
  else in_off = (long)rr * DMODEL;
  int t = threadIdx.x;
  float4 v = *(const float4*)(in + in_off + t * 4);
  float sum = v.x + v.y + v.z + v.w;
#pragma unroll
  for (int m = 1; m < 64; m <<= 1) sum += __shfl_xor(sum, m);
  __shared__ float red[4];
  __shared__ float red2[4];
  int wave = t >> 6, lane = t & 63;
  if (lane == 0) red[wave] = sum;
  __syncthreads();
  sum = red[0] + red[1] + red[2] + red[3];
  float mean = sum * (1.0f / DMODEL);
  float dx = v.x - mean, dy = v.y - mean, dz = v.z - mean, dw = v.w - mean;
  float vs = dx * dx + dy * dy + dz * dz + dw * dw;
#pragma unroll
  for (int m = 1; m < 64; m <<= 1) vs += __shfl_xor(vs, m);
  if (lane == 0) red2[wave] = vs;
  __syncthreads();
  vs = red2[0] + red2[1] + red2[2] + red2[3];
  float rstd = rsqrtf(vs * (1.0f / DMODEL) + EPS);
  float4 gv = *(const float4*)(g + t * 4);
  float4 bv = *(const float4*)(be + t * 4);
  ushort4 pk;
  pk.x = f2bf(dx * rstd * gv.x + bv.x);
  pk.y = f2bf(dy * rstd * gv.y + bv.y);
  pk.z = f2bf(dz * rstd * gv.z + bv.z);
  pk.w = f2bf(dw * rstd * gv.w + bv.w);
  *(ushort4*)(out + (long)rr * DMODEL + t * 4) = pk;
}

// ---------------- 8-wave phase-pipelined GEMM ----------------
// C = A(M,K) @ Bt(N,K)^T. BM=256, BN=128, BK=64. 512 thr = 8 waves (2M x 4N),
// per-wave 128x32. Triple-buffered LDS (144 KiB), 2-tile lookahead,
// counted vmcnt(6) once per K-tile (never 0 in steady state). Both-sides
// chunk-XOR swizzle (chunk ^= row&7) -> conflict-free ds_read_b128.
#define MODE_QKV 0
#define MODE_OPROJ 1
#define MODE_FFN1 2
#define MODE_FFN2 3

template <int MODE>
__global__ __launch_bounds__(512, 2) void gemm8(
    const unsigned short* __restrict__ A, const unsigned short* __restrict__ Bt,
    int M, int N, int K,
    const float* __restrict__ bias0, const float* __restrict__ bias1,
    const float* __restrict__ bias2,
    unsigned short* out_q, unsigned short* out_k, unsigned short* out_vt,
    const float* __restrict__ resid, float* out_f32, unsigned short* out_bf16) {
  __shared__ unsigned short AS[3][256 * 64];  // 96 KiB
  __shared__ unsigned short BS[3][128 * 64];  // 48 KiB
  // bijective XCD-aware swizzle (all grids have nwg % 8 == 0)
  int nbx = gridDim.x;
  int nwg = nbx * gridDim.y;
  int orig = blockIdx.y * nbx + blockIdx.x;
  int cpx = nwg >> 3;
  int swz = (orig & 7) * cpx + (orig >> 3);
  int bx = swz % nbx, by = swz / nbx;
  int m0 = by * 256, n0 = bx * 128;
  int t = threadIdx.x, wave = t >> 6, lane = t & 63;
  int wr = wave >> 2, wc = wave & 3;
  int qr = lane & 15, g = lane >> 4;
  const unsigned short* Ab = A + (long)m0 * K;
  const unsigned short* Bb = Bt + (long)n0 * K;
  // staging: thread covers row (L*64 + srow), pre-swizzled chunk c8
  int srow = wave * 8 + (lane >> 3);
  int sgo = ((lane & 7) ^ (lane >> 3)) * 8;

  f32x4 acc[8][2];
#pragma unroll
  for (int i = 0; i < 8; ++i)
#pragma unroll
    for (int j = 0; j < 2; ++j) acc[i][j] = (f32x4){0.f, 0.f, 0.f, 0.f};

  auto stageA = [&](int kt, int buf, int L) {
    gld_lds16(Ab + (long)(L * 64 + srow) * K + kt * 64 + sgo,
              (char*)&AS[buf][0] + L * 8192 + wave * 1024);
  };
  auto stageB = [&](int kt, int buf, int L) {
    gld_lds16(Bb + (long)(L * 64 + srow) * K + kt * 64 + sgo,
              (char*)&BS[buf][0] + L * 8192 + wave * 1024);
  };
  int xh = qr & 7;
  auto ldA = [&](const char* base, int h, int ii, int ks) {
    int ra = wr * 128 + (h * 4 + ii) * 16 + qr;
    return *(const bf16x8*)(base + ra * 128 + ((ks * 4 + g) ^ xh) * 16);
  };
  auto ldB = [&](const char* base, int jn, int ks) {
    int rb = wc * 32 + jn * 16 + qr;
    return *(const bf16x8*)(base + rb * 128 + ((ks * 4 + g) ^ xh) * 16);
  };

  const int NT = K / 64;
  // prologue: stage tiles 0 and 1
#pragma unroll
  for (int L = 0; L < 4; ++L) stageA(0, 0, L);
#pragma unroll
  for (int L = 0; L < 2; ++L) stageB(0, 0, L);
#pragma unroll
  for (int L = 0; L < 4; ++L) stageA(1, 1, L);
#pragma unroll
  for (int L = 0; L < 2; ++L) stageB(1, 1, L);
  asm volatile("s_waitcnt vmcnt(6)" ::: "memory");
  __builtin_amdgcn_sched_barrier(0);
  __builtin_amdgcn_s_barrier();

  int bread = 0, bstage = 2;
  for (int kt = 0; kt < NT; ++kt) {
    const char* Ac = (const char*)&AS[bread][0];
    const char* Bc = (const char*)&BS[bread][0];
    bool pf = (kt + 2 < NT);
    bf16x8 af[4][2], bf0[2], bf1[2];
    // ---- phase 0: quadrant (h0, j0) ----
#pragma unroll
    for (int ii = 0; ii < 4; ++ii)
#pragma unroll
      for (int ks = 0; ks < 2; ++ks) af[ii][ks] = ldA(Ac, 0, ii, ks);
#pragma unroll
    for (int ks = 0; ks < 2; ++ks) bf0[ks] = ldB(Bc, 0, ks);
    if (pf) { stageA(kt + 2, bstage, 0); stageA(kt + 2, bstage, 1); }
    __builtin_amdgcn_s_barrier();
    __builtin_amdgcn_s_setprio(1);
#pragma unroll
    for (int ii = 0; ii < 4; ++ii)
#pragma unroll
      for (int ks = 0; ks < 2; ++ks)
        acc[ii][0] = __builtin_amdgcn_mfma_f32_16x16x32_bf16(af[ii][ks], bf0[ks], acc[ii][0], 0, 0, 0);
    __builtin_amdgcn_s_setprio(0);
    __builtin_amdgcn_s_barrier();
    // ---- phase 1: quadrant (h0, j1) ----
#pragma unroll
    for (int ks = 0; ks < 2; ++ks) bf1[ks] = ldB(Bc, 1, ks);
    if (pf) { stageA(kt + 2, bstage, 2); stageA(kt + 2, bstage, 3); }
    __builtin_amdgcn_s_barrier();
    __builtin_amdgcn_s_setprio(1);
#pragma unroll
    for (int ii = 0; ii < 4; ++ii)
#pragma unroll
      for (int ks = 0; ks < 2; ++ks)
        acc[ii][1] = __builtin_amdgcn_mfma_f32_16x16x32_bf16(af[ii][ks], bf1[ks], acc[ii][1], 0, 0, 0);
    __builtin_amdgcn_s_setprio(0);
    __builtin_amdgcn_s_barrier();
    // ---- phase 2: quadrant (h1, j1) ----
#pragma unroll
    for (int ii = 0; ii < 4; ++ii)
#pragma unroll
      for (int ks = 0; ks < 2; ++ks) af[ii][ks] = ldA(Ac, 1, ii, ks);
    if (pf) { stageB(kt + 2, bstage, 0); stageB(kt + 2, bstage, 1); }
    __builtin_amdgcn_s_barrier();
    __builtin_amdgcn_s_setprio(1);
#pragma unroll
    for (int ii = 0; ii < 4; ++ii)
#pragma unroll
      for (int ks = 0; ks < 2; ++ks)
        acc[4 + ii][1] = __builtin_amdgcn_mfma_f32_16x16x32_bf16(af[ii][ks], bf1[ks], acc[4 + ii][1], 0, 0, 0);
    __builtin_amdgcn_s_setprio(0);
    __builtin_amdgcn_s_barrier();
    // ---- phase 3: quadrant (h1, j0) ----
    __builtin_amdgcn_s_setprio(1);
#pragma unroll
    for (int ii = 0; ii < 4; ++ii)
#pragma unroll
      for (int ks = 0; ks < 2; ++ks)
        acc[4 + ii][0] = __builtin_amdgcn_mfma_f32_16x16x32_bf16(af[ii][ks], bf0[ks], acc[4 + ii][0], 0, 0, 0);
    __builtin_amdgcn_s_setprio(0);
    if (kt + 2 < NT) {
      asm volatile("s_waitcnt vmcnt(6)" ::: "memory");   // tile t+1 done; t+2 in flight
    } else if (kt + 2 == NT) {
      asm volatile("s_waitcnt vmcnt(0)" ::: "memory");   // tail drain
    }
    __builtin_amdgcn_sched_barrier(0);
    __builtin_amdgcn_s_barrier();
    bread = (bread == 2) ? 0 : bread + 1;
    bstage = (bstage == 2) ? 0 : bstage + 1;
  }

  // epilogue: frag (i,j): C row = m0+wr*128+i*16+g*4+r, col = n0+wc*32+j*16+qr
#pragma unroll
  for (int i = 0; i < 8; ++i) {
#pragma unroll
    for (int j = 0; j < 2; ++j) {
      int mrow = m0 + wr * 128 + i * 16 + g * 4;
      int ncol = n0 + wc * 32 + j * 16 + qr;
      if constexpr (MODE == MODE_QKV) {
        int sel = ncol >> 10, nn = ncol & 1023;
        int h = nn >> 6, dh = nn & 63;
        const float* bptr = (sel == 0) ? bias0 : ((sel == 1) ? bias1 : bias2);
        float bias = bptr[nn];
        if (sel < 2) {
          unsigned short* dst = (sel == 0) ? out_q : out_k;
#pragma unroll
          for (int r = 0; r < 4; ++r) {
            int m = mrow + r; int bb = m >> 10, s = m & 1023;
            dst[(((long)(bb * NHEAD + h)) * S_LEN + s) * DHEAD + dh] = f2bf(acc[i][j][r] + bias);
          }
        } else {
          int m = mrow; int bb = m >> 10, s = m & 1023;
          ushort4 pk;
          pk.x = f2bf(acc[i][j][0] + bias);
          pk.y = f2bf(acc[i][j][1] + bias);
          pk.z = f2bf(acc[i][j][2] + bias);
          pk.w = f2bf(acc[i][j][3] + bias);
          *(ushort4*)&out_vt[(((long)(bb * NHEAD + h)) * DHEAD + dh) * S_LEN + s] = pk;
        }
      } else if constexpr (MODE == MODE_OPROJ) {
        float bias = bias0[ncol];
#pragma unroll
        for (int r = 0; r < 4; ++r) {
          int m = mrow + r; int bb = m >> 10, s = m & 1023;
          long oi = ((long)s * BATCH + bb) * DMODEL + ncol;
          out_f32[oi] = resid[oi] + acc[i][j][r] + bias;
        }
      } else if constexpr (MODE == MODE_FFN1) {
        float bias = bias0[ncol];
#pragma unroll
        for (int r = 0; r < 4; ++r) {
          long m = mrow + r;
          float v = acc[i][j][r] + bias;
          out_bf16[m * (long)N + ncol] = f2bf(v > 0.f ? v : 0.f);
        }
      } else {  // MODE_FFN2
        float bias = bias0[ncol];
#pragma unroll
        for (int r = 0; r < 4; ++r) {
          long m = mrow + r;
          long oi = m * (long)N + ncol;
          out_f32[oi] = resid[oi] + acc[i][j][r] + bias;
        }
      }
    }
  }
}

// ---------------- flash attention: 8 waves/block, LDS-staged K/V ----------------
__global__ __launch_bounds__(512, 4) void attn_kernel(
    const unsigned short* __restrict__ qbuf, const unsigned short* __restrict__ kbuf,
    const unsigned short* __restrict__ vtbuf, const float* __restrict__ biasm,
    unsigned short* __restrict__ out) {
  int wave = threadIdx.x >> 6, lane = threadIdx.x & 63;
  int h = blockIdx.y, b = blockIdx.z;
  int q0 = blockIdx.x * 256 + wave * 32;
  long bh = (long)(b * NHEAD + h);
  const unsigned short* Q = qbuf + bh * S_LEN * DHEAD;
  const unsigned short* Kp = kbuf + bh * S_LEN * DHEAD;
  const unsigned short* Vt = vtbuf + bh * DHEAD * S_LEN;
  const float* bm = biasm + (long)b * S_LEN;

  __shared__ unsigned short Ktile[2][64 * 64];
  __shared__ unsigned short Vtile[2][64 * 64];
  __shared__ uint2 Pbuf[8][256];
  __shared__ float AL[8][2][16];
  __shared__ float LI[8][2][16];
  uint2* Pw = Pbuf[wave];

  int qr = lane & 15, g = lane >> 4;

  int srow = wave * 8 + (lane >> 3);
  int scol = (lane & 7) ^ (srow & 7);
  const unsigned short* Ksrc = Kp + (long)srow * DHEAD + scol * 8;
  const unsigned short* Vsrc = Vt + (long)srow * S_LEN + scol * 8;

  bf16x8 qf[2][2];
#pragma unroll
  for (int f = 0; f < 2; ++f)
#pragma unroll
    for (int dhh = 0; dhh < 2; ++dhh)
      qf[f][dhh] = *(const bf16x8*)&Q[(long)(q0 + f * 16 + qr) * DHEAD + dhh * 32 + g * 8];

  f32x4 oacc[2][4];
#pragma unroll
  for (int f = 0; f < 2; ++f)
#pragma unroll
    for (int dt = 0; dt < 4; ++dt) oacc[f][dt] = (f32x4){0.f, 0.f, 0.f, 0.f};
  float m_[2] = {-1e30f, -1e30f}, l_[2] = {0.f, 0.f};

  auto stage = [&](int k0s, int buf) {
    gld_lds16(Ksrc + (long)k0s * DHEAD, (char*)&Ktile[buf][0] + wave * 1024);
    gld_lds16(Vsrc + k0s, (char*)&Vtile[buf][0] + wave * 1024);
  };

  stage(0, 0);
  int cur = 0;
  const int NT = S_LEN / 64;
  for (int t = 0; t < NT; ++t) {
    __syncthreads();
    if (t + 1 < NT) stage((t + 1) * 64, cur ^ 1);

    const char* Kt_l = (const char*)&Ktile[cur][0];
    f32x4 sacc[2][4];
#pragma unroll
    for (int f = 0; f < 2; ++f)
#pragma unroll
      for (int n = 0; n < 4; ++n) sacc[f][n] = (f32x4){0.f, 0.f, 0.f, 0.f};
#pragma unroll
    for (int n = 0; n < 4; ++n)
#pragma unroll
      for (int dhh = 0; dhh < 2; ++dhh) {
        bf16x8 kf = *(const bf16x8*)(Kt_l + (n * 16 + qr) * 128 + (((dhh * 4 + g) ^ (qr & 7)) * 16));
        sacc[0][n] = __builtin_amdgcn_mfma_f32_16x16x32_bf16(kf, qf[0][dhh], sacc[0][n], 0, 0, 0);
        sacc[1][n] = __builtin_amdgcn_mfma_f32_16x16x32_bf16(kf, qf[1][dhh], sacc[1][n], 0, 0, 0);
      }
    float4 bv[4];
#pragma unroll
    for (int n = 0; n < 4; ++n) bv[n] = *(const float4*)&bm[t * 64 + n * 16 + g * 4];

    bf16x8 paf[2][2];
#pragma unroll
    for (int f = 0; f < 2; ++f) {
      float s[16];
#pragma unroll
      for (int n = 0; n < 4; ++n) {
        const float* bvp = (const float*)&bv[n];
#pragma unroll
        for (int r = 0; r < 4; ++r) s[n * 4 + r] = fmaf(sacc[f][n][r], 0.125f, bvp[r]);
      }
      float mx = s[0];
#pragma unroll
      for (int i = 1; i < 16; ++i) mx = fmaxf(mx, s[i]);
      mx = fmaxf(mx, __shfl_xor(mx, 16));
      mx = fmaxf(mx, __shfl_xor(mx, 32));
      float mnew = fmaxf(m_[f], mx);
      float al = __expf(m_[f] - mnew);
      m_[f] = mnew;
      float ps = 0.f;
#pragma unroll
      for (int i = 0; i < 16; ++i) { s[i] = __expf(s[i] - mnew); ps += s[i]; }
      ps += __shfl_xor(ps, 16);
      ps += __shfl_xor(ps, 32);
      l_[f] = l_[f] * al + ps;
      if (lane < 16) AL[wave][f][lane] = al;
#pragma unroll
      for (int n = 0; n < 4; ++n) {
        unsigned w0, w1;
        asm("v_cvt_pk_bf16_f32 %0, %1, %2" : "=v"(w0) : "v"(s[n * 4 + 0]), "v"(s[n * 4 + 1]));
        asm("v_cvt_pk_bf16_f32 %0, %1, %2" : "=v"(w1) : "v"(s[n * 4 + 2]), "v"(s[n * 4 + 3]));
        Pw[qr * 16 + ((n * 4 + g) ^ qr)] = (uint2){w0, w1};
      }
#pragma unroll
      for (int kb = 0; kb < 2; ++kb) {
        union { uint2 u[2]; bf16x8 v; } p;
        p.u[0] = Pw[qr * 16 + ((kb * 8 + g * 2 + 0) ^ qr)];
        p.u[1] = Pw[qr * 16 + ((kb * 8 + g * 2 + 1) ^ qr)];
        paf[f][kb] = p.v;
      }
    }
#pragma unroll
    for (int f = 0; f < 2; ++f) {
      float4 alv = *(const float4*)&AL[wave][f][g * 4];
      const float* ap = (const float*)&alv;
#pragma unroll
      for (int dt = 0; dt < 4; ++dt)
#pragma unroll
        for (int r = 0; r < 4; ++r) oacc[f][dt][r] *= ap[r];
    }
    const char* Vt_l = (const char*)&Vtile[cur][0];
#pragma unroll
    for (int dt = 0; dt < 4; ++dt)
#pragma unroll
      for (int kb = 0; kb < 2; ++kb) {
        bf16x8 vf = *(const bf16x8*)(Vt_l + (dt * 16 + qr) * 128 + (((kb * 4 + g) ^ (qr & 7)) * 16));
        oacc[0][dt] = __builtin_amdgcn_mfma_f32_16x16x32_bf16(paf[0][kb], vf, oacc[0][dt], 0, 0, 0);
        oacc[1][dt] = __builtin_amdgcn_mfma_f32_16x16x32_bf16(paf[1][kb], vf, oacc[1][dt], 0, 0, 0);
      }
    cur ^= 1;
  }

#pragma unroll
  for (int f = 0; f < 2; ++f)
    if (lane < 16) LI[wave][f][lane] = 1.0f / l_[f];
#pragma unroll
  for (int f = 0; f < 2; ++f) {
    float4 lv = *(const float4*)&LI[wave][f][g * 4];
    const float* lp = (const float*)&lv;
#pragma unroll
    for (int dt = 0; dt < 4; ++dt)
#pragma unroll
      for (int r = 0; r < 4; ++r) {
        int q = q0 + f * 16 + g * 4 + r;
        int dh = dt * 16 + qr;
        out[((long)(b * S_LEN + q)) * DMODEL + h * DHEAD + dh] = f2bf(oacc[f][dt][r] * lp[r]);
      }
  }
}

// ---------------- host launcher ----------------
extern "C" void kernel_launch(void* const* d_in, const int* in_sizes, int n_in,
                              void* d_out, int out_size, void* d_ws, size_t ws_size,
                              hipStream_t stream) {
  const float* x  = (const float*)d_in[0];
  const int* kpm  = (const int*)d_in[1];
  const float* attn_bias = (const float*)d_in[2];
  const float* Wq = (const float*)d_in[3];  const float* bq = (const float*)d_in[4];
  const float* Wk = (const float*)d_in[5];  const float* bk = (const float*)d_in[6];
  const float* Wv = (const float*)d_in[7];  const float* bv = (const float*)d_in[8];
  const float* Wo = (const float*)d_in[9];  const float* bo = (const float*)d_in[10];
  const float* W1 = (const float*)d_in[11]; const float* b1 = (const float*)d_in[12];
  const float* W2 = (const float*)d_in[13]; const float* b2 = (const float*)d_in[14];
  const float* g1 = (const float*)d_in[15]; const float* be1 = (const float*)d_in[16];
  const float* g2 = (const float*)d_in[17]; const float* be2 = (const float*)d_in[18];
  const float* alpha = (const float*)d_in[19];
  float* out = (float*)d_out;

  char* ws = (char*)d_ws;
  size_t off = 0;
  auto alloc = [&](size_t bytes) { void* p = ws + off; off += (bytes + 255) & ~(size_t)255; return p; };
  unsigned short* WqkvT = (unsigned short*)alloc(3072ull * 1024 * 2);
  unsigned short* WoT   = (unsigned short*)alloc(1024ull * 1024 * 2);
  unsigned short* W1T   = (unsigned short*)alloc(4096ull * 1024 * 2);
  unsigned short* W2T   = (unsigned short*)alloc(1024ull * 4096 * 2);
  float* biasm          = (float*)alloc(8192ull * 4);
  float* y1             = (float*)alloc(8192ull * 1024 * 4);
  char* region = (char*)alloc(5ull * 16 * 1024 * 1024);
  unsigned short* x2     = (unsigned short*)(region);
  unsigned short* qb     = (unsigned short*)(region + 16ull * 1024 * 1024);
  unsigned short* kb     = (unsigned short*)(region + 32ull * 1024 * 1024);
  unsigned short* vtb    = (unsigned short*)(region + 48ull * 1024 * 1024);
  unsigned short* attn_o = (unsigned short*)(region + 64ull * 1024 * 1024);
  unsigned short* h2     = (unsigned short*)(region);                        // alias x2 (dead)
  unsigned short* ffn1   = (unsigned short*)(region + 16ull * 1024 * 1024);  // alias qb.. (dead)

  transpose_cvt<<<dim3(32, 32), 256, 0, stream>>>(Wq, WqkvT, 1024, 1024);
  transpose_cvt<<<dim3(32, 32), 256, 0, stream>>>(Wk, WqkvT + 1024ull * 1024, 1024, 1024);
  transpose_cvt<<<dim3(32, 32), 256, 0, stream>>>(Wv, WqkvT + 2048ull * 1024, 1024, 1024);
  transpose_cvt<<<dim3(32, 32), 256, 0, stream>>>(Wo, WoT, 1024, 1024);
  transpose_cvt<<<dim3(128, 32), 256, 0, stream>>>(W1, W1T, 1024, 4096);
  transpose_cvt<<<dim3(32, 128), 256, 0, stream>>>(W2, W2T, 4096, 1024);

  biasm_kernel<<<32, 256, 0, stream>>>(attn_bias, kpm, alpha, biasm);
  ln_kernel<<<8192, 256, 0, stream>>>(x, g1, be1, x2, 1);

  gemm8<MODE_QKV><<<dim3(3072 / 128, 8192 / 256), 512, 0, stream>>>(
      x2, WqkvT, 8192, 3072, 1024, bq, bk, bv, qb, kb, vtb, nullptr, nullptr, nullptr);

  attn_kernel<<<dim3(S_LEN / 256, NHEAD, BATCH), 512, 0, stream>>>(
      qb, kb, vtb, biasm, attn_o);

  gemm8<MODE_OPROJ><<<dim3(1024 / 128, 8192 / 256), 512, 0, stream>>>(
      attn_o, WoT, 8192, 1024, 1024, bo, nullptr, nullptr,
      nullptr, nullptr, nullptr, x, y1, nullptr);

  ln_kernel<<<8192, 256, 0, stream>>>(y1, g2, be2, h2, 0);

  gemm8<MODE_FFN1><<<dim3(4096 / 128, 8192 / 256), 512, 0, stream>>>(
      h2, W1T, 8192, 4096, 1024, b1, nullptr, nullptr,
      nullptr, nullptr, nullptr, nullptr, nullptr, ffn1);

  gemm8<MODE_FFN2><<<dim3(1024 / 128, 8192 / 256), 512, 0, stream>>>(
      ffn1, W2T, 8192, 1024, 4096, b2, nullptr, nullptr,
      nullptr, nullptr, nullptr, y1, out, nullptr);
}

// Round 5
// 499.703 us; speedup vs baseline: 1.4555x; 1.1223x over previous
//
#include <hip/hip_runtime.h>
#include <stdint.h>

#define S_LEN 1024
#define BATCH 8
#define DMODEL 1024
#define NHEAD 16
#define DHEAD 64
#define DFF_N 4096
#define EPS 1e-5f

typedef __attribute__((ext_vector_type(8))) short bf16x8;
typedef __attribute__((ext_vector_type(4))) float f32x4;

__device__ __forceinline__ unsigned short f2bf(float f) {
  union { float f; unsigned u; } x; x.f = f;
  unsigned r = x.u + 0x7FFFu + ((x.u >> 16) & 1u);
  return (unsigned short)(r >> 16);
}

__device__ __forceinline__ void gld_lds16(const void* g, void* l) {
  __builtin_amdgcn_global_load_lds(
      (const __attribute__((address_space(1))) void*)g,
      (__attribute__((address_space(3))) void*)l, 16, 0, 0);
}

#define BARRIER asm volatile("s_barrier" ::: "memory")

// ---------------- weight transpose + fp32->bf16 ----------------
__global__ __launch_bounds__(256) void transpose_cvt(
    const float* __restrict__ src, unsigned short* __restrict__ dst, int K, int N) {
  __shared__ float tile[32][33];
  int n0 = blockIdx.x * 32, k0 = blockIdx.y * 32;
  int tx = threadIdx.x & 31, ty = threadIdx.x >> 5;
#pragma unroll
  for (int p = 0; p < 4; ++p)
    tile[ty + p * 8][tx] = src[(long)(k0 + ty + p * 8) * N + n0 + tx];
  __syncthreads();
#pragma unroll
  for (int p = 0; p < 4; ++p)
    dst[(long)(n0 + ty + p * 8) * K + k0 + tx] = f2bf(tile[tx][ty + p * 8]);
}

// ---------------- combined mask+bias precompute ----------------
__global__ __launch_bounds__(256) void biasm_kernel(
    const float* __restrict__ bias, const int* __restrict__ kpm,
    const float* __restrict__ alpha_p, float* __restrict__ biasm) {
  int i = blockIdx.x * 256 + threadIdx.x;  // B*S = 8192
  float a = alpha_p[0];
  biasm[i] = kpm[i] ? -1e30f : bias[i] * a;
}

// ---------------- LayerNorm (row = 1024), fp32 in -> bf16 out ----------------
__global__ __launch_bounds__(256) void ln_kernel(
    const float* __restrict__ in, const float* __restrict__ g,
    const float* __restrict__ be, unsigned short* __restrict__ out, int permute) {
  int rr = blockIdx.x;
  long in_off;
  if (permute) { int b = rr >> 10, s = rr & 1023; in_off = ((long)s * BATCH + b) * DMODEL; }
  else in_off = (long)rr * DMODEL;
  int t = threadIdx.x;
  float4 v = *(const float4*)(in + in_off + t * 4);
  float sum = v.x + v.y + v.z + v.w;
#pragma unroll
  for (int m = 1; m < 64; m <<= 1) sum += __shfl_xor(sum, m);
  __shared__ float red[4];
  __shared__ float red2[4];
  int wave = t >> 6, lane = t & 63;
  if (lane == 0) red[wave] = sum;
  __syncthreads();
  sum = red[0] + red[1] + red[2] + red[3];
  float mean = sum * (1.0f / DMODEL);
  float dx = v.x - mean, dy = v.y - mean, dz = v.z - mean, dw = v.w - mean;
  float vs = dx * dx + dy * dy + dz * dz + dw * dw;
#pragma unroll
  for (int m = 1; m < 64; m <<= 1) vs += __shfl_xor(vs, m);
  if (lane == 0) red2[wave] = vs;
  __syncthreads();
  vs = red2[0] + red2[1] + red2[2] + red2[3];
  float rstd = rsqrtf(vs * (1.0f / DMODEL) + EPS);
  float4 gv = *(const float4*)(g + t * 4);
  float4 bv = *(const float4*)(be + t * 4);
  ushort4 pk;
  pk.x = f2bf(dx * rstd * gv.x + bv.x);
  pk.y = f2bf(dy * rstd * gv.y + bv.y);
  pk.z = f2bf(dz * rstd * gv.z + bv.z);
  pk.w = f2bf(dw * rstd * gv.w + bv.w);
  *(ushort4*)(out + (long)rr * DMODEL + t * 4) = pk;
}

// ---------------- m201-style phase-pipelined GEMM ----------------
// C = A(8192,K) @ Bt(N,K)^T. BM=256. WIDE: BN=256, 8 waves 2Mx4N, per-wave
// 128x64, 4 phases/K-tile x16 MFMA, vmcnt(6). NARROW: BN=128, 8 waves 4Mx2N,
// per-wave 64x64, 2 phases x16 MFMA, vmcnt(4). Slot-aligned fragment rows
// (mh*128 + ...) make each 16KB(8KB) LDS slot fully-read in one phase, so
// staging tile t+2 into a freed slot is race-free. Both-sides chunk-XOR
// swizzle (chunk ^= row&7): conflict-free ds_read_b128.
#define MODE_QKV 0
#define MODE_OPROJ 1
#define MODE_FFN1 2
#define MODE_FFN2 3

#define QUADW(MH, NH) do { \
  _Pragma("unroll") for (int i_ = 0; i_ < 4; ++i_) \
  _Pragma("unroll") for (int j_ = 0; j_ < 2; ++j_) \
  _Pragma("unroll") for (int k_ = 0; k_ < 2; ++k_) \
    acc[(MH) * 4 + i_][(NH) * 2 + j_] = __builtin_amdgcn_mfma_f32_16x16x32_bf16( \
        af[i_][k_], bfr[NH][j_][k_], acc[(MH) * 4 + i_][(NH) * 2 + j_], 0, 0, 0); \
} while (0)

#define QUADN(MH) do { \
  _Pragma("unroll") for (int i_ = 0; i_ < 2; ++i_) \
  _Pragma("unroll") for (int n_ = 0; n_ < 2; ++n_) \
  _Pragma("unroll") for (int j_ = 0; j_ < 2; ++j_) \
  _Pragma("unroll") for (int k_ = 0; k_ < 2; ++k_) \
    acc[(MH) * 2 + i_][n_ * 2 + j_] = __builtin_amdgcn_mfma_f32_16x16x32_bf16( \
        af[i_][k_], bfr[n_][j_][k_], acc[(MH) * 2 + i_][n_ * 2 + j_], 0, 0, 0); \
} while (0)

template <int MODE, bool WIDE>
__global__ __launch_bounds__(512, 2) void gemm_ph(
    const unsigned short* __restrict__ A, const unsigned short* __restrict__ Bt,
    int N, int K,
    const float* __restrict__ bias0, const float* __restrict__ bias1,
    const float* __restrict__ bias2,
    unsigned short* out_q, unsigned short* out_k, unsigned short* out_vt,
    const float* __restrict__ resid, float* out_f32, unsigned short* out_bf16) {
  constexpr int BNv = WIDE ? 256 : 128;
  constexpr int NM = WIDE ? 4 : 2;
  constexpr int BSLOT = WIDE ? 16384 : 8192;
  __shared__ unsigned short AS[32768];                 // 64 KiB: 2 buf x 2 slot x 16 KB
  __shared__ unsigned short BS[WIDE ? 32768 : 16384];  // 64/32 KiB
  char* ASb = (char*)AS;
  char* BSb = (char*)BS;

  int nbx = gridDim.x;
  int nwg = nbx * gridDim.y;
  int orig = blockIdx.y * nbx + blockIdx.x;
  int swz = (orig & 7) * (nwg >> 3) + (orig >> 3);
  int bx = swz % nbx, by = swz / nbx;
  int m0 = by * 256, n0 = bx * BNv;
  int tid = threadIdx.x, wave = tid >> 6, lane = tid & 63;
  int qr = lane & 15, g = lane >> 4, xh = qr & 7;
  int wr = WIDE ? (wave >> 2) : (wave >> 1);
  int wc = WIDE ? (wave & 3) : (wave & 1);
  int srow = wave * 8 + (lane >> 3);
  int sgo = ((lane & 7) ^ (lane >> 3)) * 8;
  const long rK64 = (long)K * 64;
  const unsigned short* AbS = A + (long)m0 * K + (long)srow * K + sgo;
  const unsigned short* BbS = Bt + (long)n0 * K + (long)srow * K + sgo;
  int c0 = (g ^ xh) * 16;
  int c1 = ((4 + g) ^ xh) * 16;
  int roA = (WIDE ? wr * 64 : wr * 32) + qr;
  int roB = wc * 32 + qr;

  f32x4 acc[2 * NM][4];
#pragma unroll
  for (int i = 0; i < 2 * NM; ++i)
#pragma unroll
    for (int j = 0; j < 4; ++j) acc[i][j] = (f32x4){0.f, 0.f, 0.f, 0.f};
  bf16x8 af[NM][2];
  bf16x8 bfr[2][2][2];

  auto stA = [&](int kt, int slot, int L) {
    gld_lds16(AbS + slot * 2 * rK64 + L * rK64 + kt * 64,
              ASb + ((kt & 1) * 2 + slot) * 16384 + L * 8192 + wave * 1024);
  };
  auto stB = [&](int kt, int slot, int L) {
    if constexpr (WIDE)
      gld_lds16(BbS + slot * 2 * rK64 + L * rK64 + kt * 64,
                BSb + ((kt & 1) * 2 + slot) * 16384 + L * 8192 + wave * 1024);
    else
      gld_lds16(BbS + slot * rK64 + kt * 64,
                BSb + ((kt & 1) * 2 + slot) * 8192 + wave * 1024);
  };
  auto ldAh = [&](int buf, int mh) {
    const char* base = ASb + (buf * 2 + mh) * 16384 + roA * 128;
#pragma unroll
    for (int i = 0; i < NM; ++i) {
      af[i][0] = *(const bf16x8*)(base + i * 2048 + c0);
      af[i][1] = *(const bf16x8*)(base + i * 2048 + c1);
    }
  };
  auto ldBh = [&](bf16x8 (&bq)[2][2], int buf, int nh) {
    const char* base = BSb + (buf * 2 + nh) * BSLOT + roB * 128;
#pragma unroll
    for (int j = 0; j < 2; ++j) {
      bq[j][0] = *(const bf16x8*)(base + j * 2048 + c0);
      bq[j][1] = *(const bf16x8*)(base + j * 2048 + c1);
    }
  };

  const int NT = K / 64;
  // prologue: tile0 full, tile1 all but A1
  if constexpr (WIDE) {
    stA(0, 0, 0); stA(0, 0, 1); stA(0, 1, 0); stA(0, 1, 1);
    stB(0, 0, 0); stB(0, 0, 1); stB(0, 1, 0); stB(0, 1, 1);
    stA(1, 0, 0); stA(1, 0, 1); stB(1, 0, 0); stB(1, 0, 1); stB(1, 1, 0); stB(1, 1, 1);
    asm volatile("s_waitcnt vmcnt(6)" ::: "memory");
  } else {
    stA(0, 0, 0); stA(0, 0, 1); stA(0, 1, 0); stA(0, 1, 1);
    stB(0, 0, 0); stB(0, 1, 0);
    stA(1, 0, 0); stA(1, 0, 1); stB(1, 0, 0); stB(1, 1, 0);
    asm volatile("s_waitcnt vmcnt(4)" ::: "memory");
  }
  __builtin_amdgcn_sched_barrier(0);
  BARRIER;

  for (int kt = 0; kt < NT; ++kt) {
    int buf = kt & 1;
    if constexpr (WIDE) {
      // phase 1: quadrant (0,0); stage (t+1).A1
      ldAh(buf, 0);
      ldBh(bfr[0], buf, 0);
      if (kt + 1 < NT) { stA(kt + 1, 1, 0); stA(kt + 1, 1, 1); }
      BARRIER; __builtin_amdgcn_sched_barrier(0);
      __builtin_amdgcn_s_setprio(1); QUADW(0, 0); __builtin_amdgcn_s_setprio(0);
      BARRIER;
      // phase 2: quadrant (0,1); stage (t+2).A0
      ldBh(bfr[1], buf, 1);
      if (kt + 2 < NT) { stA(kt + 2, 0, 0); stA(kt + 2, 0, 1); }
      BARRIER; __builtin_amdgcn_sched_barrier(0);
      __builtin_amdgcn_s_setprio(1); QUADW(0, 1); __builtin_amdgcn_s_setprio(0);
      BARRIER;
      // phase 3: quadrant (1,1); stage (t+2).B0
      ldAh(buf, 1);
      if (kt + 2 < NT) { stB(kt + 2, 0, 0); stB(kt + 2, 0, 1); }
      BARRIER; __builtin_amdgcn_sched_barrier(0);
      __builtin_amdgcn_s_setprio(1); QUADW(1, 1); __builtin_amdgcn_s_setprio(0);
      BARRIER;
      // phase 4: quadrant (1,0); stage (t+2).B1
      if (kt + 2 < NT) { stB(kt + 2, 1, 0); stB(kt + 2, 1, 1); }
      BARRIER; __builtin_amdgcn_sched_barrier(0);
      __builtin_amdgcn_s_setprio(1); QUADW(1, 0); __builtin_amdgcn_s_setprio(0);
      if (kt + 2 < NT) asm volatile("s_waitcnt vmcnt(6)" ::: "memory");
      else asm volatile("s_waitcnt vmcnt(0)" ::: "memory");
      __builtin_amdgcn_sched_barrier(0);
      BARRIER;
    } else {
      // phase 1: mh=0, all N; stage (t+1).A1
      ldAh(buf, 0);
      ldBh(bfr[0], buf, 0);
      ldBh(bfr[1], buf, 1);
      if (kt + 1 < NT) { stA(kt + 1, 1, 0); stA(kt + 1, 1, 1); }
      BARRIER; __builtin_amdgcn_sched_barrier(0);
      __builtin_amdgcn_s_setprio(1); QUADN(0); __builtin_amdgcn_s_setprio(0);
      BARRIER;
      // phase 2: mh=1; stage (t+2).{A0,B0,B1}
      ldAh(buf, 1);
      if (kt + 2 < NT) { stA(kt + 2, 0, 0); stA(kt + 2, 0, 1); stB(kt + 2, 0, 0); stB(kt + 2, 1, 0); }
      BARRIER; __builtin_amdgcn_sched_barrier(0);
      __builtin_amdgcn_s_setprio(1); QUADN(1); __builtin_amdgcn_s_setprio(0);
      if (kt + 2 < NT) asm volatile("s_waitcnt vmcnt(4)" ::: "memory");
      else asm volatile("s_waitcnt vmcnt(0)" ::: "memory");
      __builtin_amdgcn_sched_barrier(0);
      BARRIER;
    }
  }

  // epilogue
#pragma unroll
  for (int I = 0; I < 2 * NM; ++I) {
#pragma unroll
    for (int J = 0; J < 4; ++J) {
      int mrow, ncol;
      if constexpr (WIDE) {
        mrow = m0 + (I >> 2) * 128 + wr * 64 + (I & 3) * 16 + g * 4;
        ncol = n0 + (J >> 1) * 128 + wc * 32 + (J & 1) * 16 + qr;
      } else {
        mrow = m0 + (I >> 1) * 128 + wr * 32 + (I & 1) * 16 + g * 4;
        ncol = n0 + (J >> 1) * 64 + wc * 32 + (J & 1) * 16 + qr;
      }
      if constexpr (MODE == MODE_QKV) {
        int sel = ncol >> 10, nn = ncol & 1023;
        int h = nn >> 6, dh = nn & 63;
        const float* bptr = (sel == 0) ? bias0 : ((sel == 1) ? bias1 : bias2);
        float bias = bptr[nn];
        if (sel < 2) {
          unsigned short* dst = (sel == 0) ? out_q : out_k;
#pragma unroll
          for (int r = 0; r < 4; ++r) {
            int m = mrow + r; int bb = m >> 10, s = m & 1023;
            dst[(((long)(bb * NHEAD + h)) * S_LEN + s) * DHEAD + dh] = f2bf(acc[I][J][r] + bias);
          }
        } else {
          int m = mrow; int bb = m >> 10, s = m & 1023;
          ushort4 pk;
          pk.x = f2bf(acc[I][J][0] + bias);
          pk.y = f2bf(acc[I][J][1] + bias);
          pk.z = f2bf(acc[I][J][2] + bias);
          pk.w = f2bf(acc[I][J][3] + bias);
          *(ushort4*)&out_vt[(((long)(bb * NHEAD + h)) * DHEAD + dh) * S_LEN + s] = pk;
        }
      } else if constexpr (MODE == MODE_OPROJ) {
        float bias = bias0[ncol];
#pragma unroll
        for (int r = 0; r < 4; ++r) {
          int m = mrow + r; int bb = m >> 10, s = m & 1023;
          long oi = ((long)s * BATCH + bb) * DMODEL + ncol;
          out_f32[oi] = resid[oi] + acc[I][J][r] + bias;
        }
      } else if constexpr (MODE == MODE_FFN1) {
        float bias = bias0[ncol];
#pragma unroll
        for (int r = 0; r < 4; ++r) {
          long m = mrow + r;
          float v = acc[I][J][r] + bias;
          out_bf16[m * (long)N + ncol] = f2bf(v > 0.f ? v : 0.f);
        }
      } else {  // MODE_FFN2
        float bias = bias0[ncol];
#pragma unroll
        for (int r = 0; r < 4; ++r) {
          long m = mrow + r;
          long oi = m * (long)N + ncol;
          out_f32[oi] = resid[oi] + acc[I][J][r] + bias;
        }
      }
    }
  }
}

// ---------------- flash attention: 8 waves/block, LDS-staged K/V ----------------
__global__ __launch_bounds__(512, 4) void attn_kernel(
    const unsigned short* __restrict__ qbuf, const unsigned short* __restrict__ kbuf,
    const unsigned short* __restrict__ vtbuf, const float* __restrict__ biasm,
    unsigned short* __restrict__ out) {
  int wave = threadIdx.x >> 6, lane = threadIdx.x & 63;
  int h = blockIdx.y, b = blockIdx.z;
  int q0 = blockIdx.x * 256 + wave * 32;
  long bh = (long)(b * NHEAD + h);
  const unsigned short* Q = qbuf + bh * S_LEN * DHEAD;
  const unsigned short* Kp = kbuf + bh * S_LEN * DHEAD;
  const unsigned short* Vt = vtbuf + bh * DHEAD * S_LEN;
  const float* bm = biasm + (long)b * S_LEN;

  __shared__ unsigned short Ktile[2][64 * 64];
  __shared__ unsigned short Vtile[2][64 * 64];
  __shared__ uint2 Pbuf[8][256];
  __shared__ float AL[8][2][16];
  __shared__ float LI[8][2][16];
  uint2* Pw = Pbuf[wave];

  int qr = lane & 15, g = lane >> 4;

  int srow = wave * 8 + (lane >> 3);
  int scol = (lane & 7) ^ (srow & 7);
  const unsigned short* Ksrc = Kp + (long)srow * DHEAD + scol * 8;
  const unsigned short* Vsrc = Vt + (long)srow * S_LEN + scol * 8;

  bf16x8 qf[2][2];
#pragma unroll
  for (int f = 0; f < 2; ++f)
#pragma unroll
    for (int dhh = 0; dhh < 2; ++dhh)
      qf[f][dhh] = *(const bf16x8*)&Q[(long)(q0 + f * 16 + qr) * DHEAD + dhh * 32 + g * 8];

  f32x4 oacc[2][4];
#pragma unroll
  for (int f = 0; f < 2; ++f)
#pragma unroll
    for (int dt = 0; dt < 4; ++dt) oacc[f][dt] = (f32x4){0.f, 0.f, 0.f, 0.f};
  float m_[2] = {-1e30f, -1e30f}, l_[2] = {0.f, 0.f};

  auto stage = [&](int k0s, int buf) {
    gld_lds16(Ksrc + (long)k0s * DHEAD, (char*)&Ktile[buf][0] + wave * 1024);
    gld_lds16(Vsrc + k0s, (char*)&Vtile[buf][0] + wave * 1024);
  };

  stage(0, 0);
  int cur = 0;
  const int NT = S_LEN / 64;
  for (int t = 0; t < NT; ++t) {
    __syncthreads();
    if (t + 1 < NT) stage((t + 1) * 64, cur ^ 1);

    const char* Kt_l = (const char*)&Ktile[cur][0];
    f32x4 sacc[2][4];
#pragma unroll
    for (int f = 0; f < 2; ++f)
#pragma unroll
      for (int n = 0; n < 4; ++n) sacc[f][n] = (f32x4){0.f, 0.f, 0.f, 0.f};
#pragma unroll
    for (int n = 0; n < 4; ++n)
#pragma unroll
      for (int dhh = 0; dhh < 2; ++dhh) {
        bf16x8 kf = *(const bf16x8*)(Kt_l + (n * 16 + qr) * 128 + (((dhh * 4 + g) ^ (qr & 7)) * 16));
        sacc[0][n] = __builtin_amdgcn_mfma_f32_16x16x32_bf16(kf, qf[0][dhh], sacc[0][n], 0, 0, 0);
        sacc[1][n] = __builtin_amdgcn_mfma_f32_16x16x32_bf16(kf, qf[1][dhh], sacc[1][n], 0, 0, 0);
      }
    float4 bv[4];
#pragma unroll
    for (int n = 0; n < 4; ++n) bv[n] = *(const float4*)&bm[t * 64 + n * 16 + g * 4];

    bf16x8 paf[2][2];
#pragma unroll
    for (int f = 0; f < 2; ++f) {
      float s[16];
#pragma unroll
      for (int n = 0; n < 4; ++n) {
        const float* bvp = (const float*)&bv[n];
#pragma unroll
        for (int r = 0; r < 4; ++r) s[n * 4 + r] = fmaf(sacc[f][n][r], 0.125f, bvp[r]);
      }
      float mx = s[0];
#pragma unroll
      for (int i = 1; i < 16; ++i) mx = fmaxf(mx, s[i]);
      mx = fmaxf(mx, __shfl_xor(mx, 16));
      mx = fmaxf(mx, __shfl_xor(mx, 32));
      float mnew = fmaxf(m_[f], mx);
      float al = __expf(m_[f] - mnew);
      m_[f] = mnew;
      float ps = 0.f;
#pragma unroll
      for (int i = 0; i < 16; ++i) { s[i] = __expf(s[i] - mnew); ps += s[i]; }
      ps += __shfl_xor(ps, 16);
      ps += __shfl_xor(ps, 32);
      l_[f] = l_[f] * al + ps;
      if (lane < 16) AL[wave][f][lane] = al;
#pragma unroll
      for (int n = 0; n < 4; ++n) {
        unsigned w0, w1;
        asm("v_cvt_pk_bf16_f32 %0, %1, %2" : "=v"(w0) : "v"(s[n * 4 + 0]), "v"(s[n * 4 + 1]));
        asm("v_cvt_pk_bf16_f32 %0, %1, %2" : "=v"(w1) : "v"(s[n * 4 + 2]), "v"(s[n * 4 + 3]));
        Pw[qr * 16 + ((n * 4 + g) ^ qr)] = (uint2){w0, w1};
      }
#pragma unroll
      for (int kb = 0; kb < 2; ++kb) {
        union { uint2 u[2]; bf16x8 v; } p;
        p.u[0] = Pw[qr * 16 + ((kb * 8 + g * 2 + 0) ^ qr)];
        p.u[1] = Pw[qr * 16 + ((kb * 8 + g * 2 + 1) ^ qr)];
        paf[f][kb] = p.v;
      }
    }
#pragma unroll
    for (int f = 0; f < 2; ++f) {
      float4 alv = *(const float4*)&AL[wave][f][g * 4];
      const float* ap = (const float*)&alv;
#pragma unroll
      for (int dt = 0; dt < 4; ++dt)
#pragma unroll
        for (int r = 0; r < 4; ++r) oacc[f][dt][r] *= ap[r];
    }
    const char* Vt_l = (const char*)&Vtile[cur][0];
#pragma unroll
    for (int dt = 0; dt < 4; ++dt)
#pragma unroll
      for (int kb = 0; kb < 2; ++kb) {
        bf16x8 vf = *(const bf16x8*)(Vt_l + (dt * 16 + qr) * 128 + (((kb * 4 + g) ^ (qr & 7)) * 16));
        oacc[0][dt] = __builtin_amdgcn_mfma_f32_16x16x32_bf16(paf[0][kb], vf, oacc[0][dt], 0, 0, 0);
        oacc[1][dt] = __builtin_amdgcn_mfma_f32_16x16x32_bf16(paf[1][kb], vf, oacc[1][dt], 0, 0, 0);
      }
    cur ^= 1;
  }

#pragma unroll
  for (int f = 0; f < 2; ++f)
    if (lane < 16) LI[wave][f][lane] = 1.0f / l_[f];
#pragma unroll
  for (int f = 0; f < 2; ++f) {
    float4 lv = *(const float4*)&LI[wave][f][g * 4];
    const float* lp = (const float*)&lv;
#pragma unroll
    for (int dt = 0; dt < 4; ++dt)
#pragma unroll
      for (int r = 0; r < 4; ++r) {
        int q = q0 + f * 16 + g * 4 + r;
        int dh = dt * 16 + qr;
        out[((long)(b * S_LEN + q)) * DMODEL + h * DHEAD + dh] = f2bf(oacc[f][dt][r] * lp[r]);
      }
  }
}

// ---------------- host launcher ----------------
extern "C" void kernel_launch(void* const* d_in, const int* in_sizes, int n_in,
                              void* d_out, int out_size, void* d_ws, size_t ws_size,
                              hipStream_t stream) {
  const float* x  = (const float*)d_in[0];
  const int* kpm  = (const int*)d_in[1];
  const float* attn_bias = (const float*)d_in[2];
  const float* Wq = (const float*)d_in[3];  const float* bq = (const float*)d_in[4];
  const float* Wk = (const float*)d_in[5];  const float* bk = (const float*)d_in[6];
  const float* Wv = (const float*)d_in[7];  const float* bv = (const float*)d_in[8];
  const float* Wo = (const float*)d_in[9];  const float* bo = (const float*)d_in[10];
  const float* W1 = (const float*)d_in[11]; const float* b1 = (const float*)d_in[12];
  const float* W2 = (const float*)d_in[13]; const float* b2 = (const float*)d_in[14];
  const float* g1 = (const float*)d_in[15]; const float* be1 = (const float*)d_in[16];
  const float* g2 = (const float*)d_in[17]; const float* be2 = (const float*)d_in[18];
  const float* alpha = (const float*)d_in[19];
  float* out = (float*)d_out;

  char* ws = (char*)d_ws;
  size_t off = 0;
  auto alloc = [&](size_t bytes) { void* p = ws + off; off += (bytes + 255) & ~(size_t)255; return p; };
  unsigned short* WqkvT = (unsigned short*)alloc(3072ull * 1024 * 2);
  unsigned short* WoT   = (unsigned short*)alloc(1024ull * 1024 * 2);
  unsigned short* W1T   = (unsigned short*)alloc(4096ull * 1024 * 2);
  unsigned short* W2T   = (unsigned short*)alloc(1024ull * 4096 * 2);
  float* biasm          = (float*)alloc(8192ull * 4);
  float* y1             = (float*)alloc(8192ull * 1024 * 4);
  char* region = (char*)alloc(5ull * 16 * 1024 * 1024);
  unsigned short* x2     = (unsigned short*)(region);
  unsigned short* qb     = (unsigned short*)(region + 16ull * 1024 * 1024);
  unsigned short* kb     = (unsigned short*)(region + 32ull * 1024 * 1024);
  unsigned short* vtb    = (unsigned short*)(region + 48ull * 1024 * 1024);
  unsigned short* attn_o = (unsigned short*)(region + 64ull * 1024 * 1024);
  unsigned short* h2     = (unsigned short*)(region);                        // alias x2 (dead)
  unsigned short* ffn1   = (unsigned short*)(region + 16ull * 1024 * 1024);  // alias qb.. (dead)

  transpose_cvt<<<dim3(32, 32), 256, 0, stream>>>(Wq, WqkvT, 1024, 1024);
  transpose_cvt<<<dim3(32, 32), 256, 0, stream>>>(Wk, WqkvT + 1024ull * 1024, 1024, 1024);
  transpose_cvt<<<dim3(32, 32), 256, 0, stream>>>(Wv, WqkvT + 2048ull * 1024, 1024, 1024);
  transpose_cvt<<<dim3(32, 32), 256, 0, stream>>>(Wo, WoT, 1024, 1024);
  transpose_cvt<<<dim3(128, 32), 256, 0, stream>>>(W1, W1T, 1024, 4096);
  transpose_cvt<<<dim3(32, 128), 256, 0, stream>>>(W2, W2T, 4096, 1024);

  biasm_kernel<<<32, 256, 0, stream>>>(attn_bias, kpm, alpha, biasm);
  ln_kernel<<<8192, 256, 0, stream>>>(x, g1, be1, x2, 1);

  gemm_ph<MODE_QKV, false><<<dim3(3072 / 128, 32), 512, 0, stream>>>(
      x2, WqkvT, 3072, 1024, bq, bk, bv, qb, kb, vtb, nullptr, nullptr, nullptr);

  attn_kernel<<<dim3(S_LEN / 256, NHEAD, BATCH), 512, 0, stream>>>(
      qb, kb, vtb, biasm, attn_o);

  gemm_ph<MODE_OPROJ, false><<<dim3(1024 / 128, 32), 512, 0, stream>>>(
      attn_o, WoT, 1024, 1024, bo, nullptr, nullptr,
      nullptr, nullptr, nullptr, x, y1, nullptr);

  ln_kernel<<<8192, 256, 0, stream>>>(y1, g2, be2, h2, 0);

  gemm_ph<MODE_FFN1, true><<<dim3(4096 / 256, 32), 512, 0, stream>>>(
      h2, W1T, 4096, 1024, b1, nullptr, nullptr,
      nullptr, nullptr, nullptr, nullptr, nullptr, ffn1);

  gemm_ph<MODE_FFN2, false><<<dim3(1024 / 128, 32), 512, 0, stream>>>(
      ffn1, W2T, 1024, 4096, b2, nullptr, nullptr,
      nullptr, nullptr, nullptr, y1, out, nullptr);
}

// Round 6
// 488.532 us; speedup vs baseline: 1.4888x; 1.0229x over previous
//
#include <hip/hip_runtime.h>
#include <stdint.h>

#define S_LEN 1024
#define BATCH 8
#define DMODEL 1024
#define NHEAD 16
#define DHEAD 64
#define DFF_N 4096
#define EPS 1e-5f

typedef __attribute__((ext_vector_type(8))) short bf16x8;
typedef __attribute__((ext_vector_type(4))) float f32x4;

__device__ __forceinline__ unsigned short f2bf(float f) {
  union { float f; unsigned u; } x; x.f = f;
  unsigned r = x.u + 0x7FFFu + ((x.u >> 16) & 1u);
  return (unsigned short)(r >> 16);
}
__device__ __forceinline__ float bf2f(unsigned short u) {
  union { unsigned u; float f; } x; x.u = ((unsigned)u) << 16; return x.f;
}

__device__ __forceinline__ void gld_lds16(const void* g, void* l) {
  __builtin_amdgcn_global_load_lds(
      (const __attribute__((address_space(1))) void*)g,
      (__attribute__((address_space(3))) void*)l, 16, 0, 0);
}

#define BARRIER asm volatile("s_barrier" ::: "memory")

// ---------------- fused prep: all weight transposes + biasm ----------------
__global__ __launch_bounds__(256) void prep_kernel(
    const float* __restrict__ Wq, const float* __restrict__ Wk,
    const float* __restrict__ Wv, const float* __restrict__ Wo,
    const float* __restrict__ W1, const float* __restrict__ W2,
    unsigned short* __restrict__ WqkvT, unsigned short* __restrict__ WoT,
    unsigned short* __restrict__ W1T, unsigned short* __restrict__ W2T,
    const float* __restrict__ bias, const int* __restrict__ kpm,
    const float* __restrict__ alpha_p, float* __restrict__ biasm) {
  int bid = blockIdx.x;
  if (bid < 32) {
    int i = bid * 256 + threadIdx.x;
    float a = alpha_p[0];
    biasm[i] = kpm[i] ? -1e30f : bias[i] * a;
    return;
  }
  bid -= 32;
  const float* src; unsigned short* dst; int K, N, tile;
  if (bid < 1024)      { src = Wq; dst = WqkvT;                 K = 1024; N = 1024; tile = bid; }
  else if (bid < 2048) { src = Wk; dst = WqkvT + 1024 * 1024;   K = 1024; N = 1024; tile = bid - 1024; }
  else if (bid < 3072) { src = Wv; dst = WqkvT + 2048 * 1024;   K = 1024; N = 1024; tile = bid - 2048; }
  else if (bid < 4096) { src = Wo; dst = WoT;                   K = 1024; N = 1024; tile = bid - 3072; }
  else if (bid < 8192) { src = W1; dst = W1T;                   K = 1024; N = 4096; tile = bid - 4096; }
  else                 { src = W2; dst = W2T;                   K = 4096; N = 1024; tile = bid - 8192; }
  int nx = N >> 5;
  int n0 = (tile % nx) * 32, k0 = (tile / nx) * 32;
  __shared__ float tilebuf[32][33];
  int tx = threadIdx.x & 31, ty = threadIdx.x >> 5;
#pragma unroll
  for (int p = 0; p < 4; ++p)
    tilebuf[ty + p * 8][tx] = src[(long)(k0 + ty + p * 8) * N + n0 + tx];
  __syncthreads();
#pragma unroll
  for (int p = 0; p < 4; ++p)
    dst[(long)(n0 + ty + p * 8) * K + k0 + tx] = f2bf(tilebuf[tx][ty + p * 8]);
}

// ---------------- LayerNorm (row = 1024), fp32 in -> bf16 out ----------------
__global__ __launch_bounds__(256) void ln_kernel(
    const float* __restrict__ in, const float* __restrict__ g,
    const float* __restrict__ be, unsigned short* __restrict__ out, int permute) {
  int rr = blockIdx.x;
  long in_off;
  if (permute) { int b = rr >> 10, s = rr & 1023; in_off = ((long)s * BATCH + b) * DMODEL; }
  else in_off = (long)rr * DMODEL;
  int t = threadIdx.x;
  float4 v = *(const float4*)(in + in_off + t * 4);
  float sum = v.x + v.y + v.z + v.w;
#pragma unroll
  for (int m = 1; m < 64; m <<= 1) sum += __shfl_xor(sum, m);
  __shared__ float red[4];
  __shared__ float red2[4];
  int wave = t >> 6, lane = t & 63;
  if (lane == 0) red[wave] = sum;
  __syncthreads();
  sum = red[0] + red[1] + red[2] + red[3];
  float mean = sum * (1.0f / DMODEL);
  float dx = v.x - mean, dy = v.y - mean, dz = v.z - mean, dw = v.w - mean;
  float vs = dx * dx + dy * dy + dz * dz + dw * dw;
#pragma unroll
  for (int m = 1; m < 64; m <<= 1) vs += __shfl_xor(vs, m);
  if (lane == 0) red2[wave] = vs;
  __syncthreads();
  vs = red2[0] + red2[1] + red2[2] + red2[3];
  float rstd = rsqrtf(vs * (1.0f / DMODEL) + EPS);
  float4 gv = *(const float4*)(g + t * 4);
  float4 bv = *(const float4*)(be + t * 4);
  ushort4 pk;
  pk.x = f2bf(dx * rstd * gv.x + bv.x);
  pk.y = f2bf(dy * rstd * gv.y + bv.y);
  pk.z = f2bf(dz * rstd * gv.z + bv.z);
  pk.w = f2bf(dw * rstd * gv.w + bv.w);
  *(ushort4*)(out + (long)rr * DMODEL + t * 4) = pk;
}

// ---------------- split-K reduce for FFN2 ----------------
__global__ __launch_bounds__(256) void ffn2_reduce(
    const unsigned short* __restrict__ p0, const unsigned short* __restrict__ p1,
    const float* __restrict__ resid, const float* __restrict__ b2,
    float* __restrict__ out) {
  long i = ((long)blockIdx.x * 256 + threadIdx.x) * 4;
  ushort4 a = *(const ushort4*)(p0 + i);
  ushort4 b = *(const ushort4*)(p1 + i);
  float4 r = *(const float4*)(resid + i);
  int nc = (int)(i & 1023);
  float4 bb = *(const float4*)(b2 + nc);
  float4 o;
  o.x = bf2f(a.x) + bf2f(b.x) + r.x + bb.x;
  o.y = bf2f(a.y) + bf2f(b.y) + r.y + bb.y;
  o.z = bf2f(a.z) + bf2f(b.z) + r.z + bb.z;
  o.w = bf2f(a.w) + bf2f(b.w) + r.w + bb.w;
  *(float4*)(out + i) = o;
}

// ---------------- m201-style phase-pipelined GEMM ----------------
#define MODE_QKV 0
#define MODE_OPROJ 1
#define MODE_FFN1 2
#define MODE_FFN2 3
#define MODE_PART 4

#define QUADW(MH, NH) do { \
  _Pragma("unroll") for (int i_ = 0; i_ < 4; ++i_) \
  _Pragma("unroll") for (int j_ = 0; j_ < 2; ++j_) \
  _Pragma("unroll") for (int k_ = 0; k_ < 2; ++k_) \
    acc[(MH) * 4 + i_][(NH) * 2 + j_] = __builtin_amdgcn_mfma_f32_16x16x32_bf16( \
        af[i_][k_], bfr[NH][j_][k_], acc[(MH) * 4 + i_][(NH) * 2 + j_], 0, 0, 0); \
} while (0)

#define QUADN(MH) do { \
  _Pragma("unroll") for (int i_ = 0; i_ < 2; ++i_) \
  _Pragma("unroll") for (int n_ = 0; n_ < 2; ++n_) \
  _Pragma("unroll") for (int j_ = 0; j_ < 2; ++j_) \
  _Pragma("unroll") for (int k_ = 0; k_ < 2; ++k_) \
    acc[(MH) * 2 + i_][n_ * 2 + j_] = __builtin_amdgcn_mfma_f32_16x16x32_bf16( \
        af[i_][k_], bfr[n_][j_][k_], acc[(MH) * 2 + i_][n_ * 2 + j_], 0, 0, 0); \
} while (0)

template <int MODE, bool WIDE>
__global__ __launch_bounds__(512, 2) void gemm_ph(
    const unsigned short* __restrict__ A, const unsigned short* __restrict__ Bt,
    int N, int K, int NT,
    const float* __restrict__ bias0, const float* __restrict__ bias1,
    const float* __restrict__ bias2,
    unsigned short* out_q, unsigned short* out_k, unsigned short* out_vt,
    const float* __restrict__ resid, float* out_f32, unsigned short* out_bf16) {
  constexpr int BNv = WIDE ? 256 : 128;
  constexpr int NM = WIDE ? 4 : 2;
  constexpr int BSLOT = WIDE ? 16384 : 8192;
  __shared__ unsigned short AS[32768];
  __shared__ unsigned short BS[WIDE ? 32768 : 16384];
  char* ASb = (char*)AS;
  char* BSb = (char*)BS;

  int nbx = gridDim.x;
  int nwg = nbx * gridDim.y;
  int orig = blockIdx.y * nbx + blockIdx.x;
  int swz = (orig & 7) * (nwg >> 3) + (orig >> 3);
  int bx = swz % nbx, by = swz / nbx;
  int m0 = by * 256, n0 = bx * BNv;
  int kbase = blockIdx.z * NT * 64;
  int tid = threadIdx.x, wave = tid >> 6, lane = tid & 63;
  int qr = lane & 15, g = lane >> 4, xh = qr & 7;
  int wr = WIDE ? (wave >> 2) : (wave >> 1);
  int wc = WIDE ? (wave & 3) : (wave & 1);
  int srow = wave * 8 + (lane >> 3);
  int sgo = ((lane & 7) ^ (lane >> 3)) * 8;
  const long rK64 = (long)K * 64;
  const unsigned short* AbS = A + (long)m0 * K + (long)srow * K + sgo + kbase;
  const unsigned short* BbS = Bt + (long)n0 * K + (long)srow * K + sgo + kbase;
  int c0 = (g ^ xh) * 16;
  int c1 = ((4 + g) ^ xh) * 16;
  int roA = (WIDE ? wr * 64 : wr * 32) + qr;
  int roB = wc * 32 + qr;

  f32x4 acc[2 * NM][4];
#pragma unroll
  for (int i = 0; i < 2 * NM; ++i)
#pragma unroll
    for (int j = 0; j < 4; ++j) acc[i][j] = (f32x4){0.f, 0.f, 0.f, 0.f};
  bf16x8 af[NM][2];
  bf16x8 bfr[2][2][2];

  auto stA = [&](int kt, int slot, int L) {
    gld_lds16(AbS + slot * 2 * rK64 + L * rK64 + kt * 64,
              ASb + ((kt & 1) * 2 + slot) * 16384 + L * 8192 + wave * 1024);
  };
  auto stB = [&](int kt, int slot, int L) {
    if constexpr (WIDE)
      gld_lds16(BbS + slot * 2 * rK64 + L * rK64 + kt * 64,
                BSb + ((kt & 1) * 2 + slot) * 16384 + L * 8192 + wave * 1024);
    else
      gld_lds16(BbS + slot * rK64 + kt * 64,
                BSb + ((kt & 1) * 2 + slot) * 8192 + wave * 1024);
  };
  auto ldAh = [&](int buf, int mh) {
    const char* base = ASb + (buf * 2 + mh) * 16384 + roA * 128;
#pragma unroll
    for (int i = 0; i < NM; ++i) {
      af[i][0] = *(const bf16x8*)(base + i * 2048 + c0);
      af[i][1] = *(const bf16x8*)(base + i * 2048 + c1);
    }
  };
  auto ldBh = [&](bf16x8 (&bq)[2][2], int buf, int nh) {
    const char* base = BSb + (buf * 2 + nh) * BSLOT + roB * 128;
#pragma unroll
    for (int j = 0; j < 2; ++j) {
      bq[j][0] = *(const bf16x8*)(base + j * 2048 + c0);
      bq[j][1] = *(const bf16x8*)(base + j * 2048 + c1);
    }
  };

  if constexpr (WIDE) {
    stA(0, 0, 0); stA(0, 0, 1); stA(0, 1, 0); stA(0, 1, 1);
    stB(0, 0, 0); stB(0, 0, 1); stB(0, 1, 0); stB(0, 1, 1);
    stA(1, 0, 0); stA(1, 0, 1); stB(1, 0, 0); stB(1, 0, 1); stB(1, 1, 0); stB(1, 1, 1);
    asm volatile("s_waitcnt vmcnt(6)" ::: "memory");
  } else {
    stA(0, 0, 0); stA(0, 0, 1); stA(0, 1, 0); stA(0, 1, 1);
    stB(0, 0, 0); stB(0, 1, 0);
    stA(1, 0, 0); stA(1, 0, 1); stB(1, 0, 0); stB(1, 1, 0);
    asm volatile("s_waitcnt vmcnt(4)" ::: "memory");
  }
  __builtin_amdgcn_sched_barrier(0);
  BARRIER;

  for (int kt = 0; kt < NT; ++kt) {
    int buf = kt & 1;
    if constexpr (WIDE) {
      ldAh(buf, 0);
      ldBh(bfr[0], buf, 0);
      if (kt + 1 < NT) { stA(kt + 1, 1, 0); stA(kt + 1, 1, 1); }
      BARRIER; __builtin_amdgcn_sched_barrier(0);
      __builtin_amdgcn_s_setprio(1); QUADW(0, 0); __builtin_amdgcn_s_setprio(0);
      BARRIER;
      ldBh(bfr[1], buf, 1);
      if (kt + 2 < NT) { stA(kt + 2, 0, 0); stA(kt + 2, 0, 1); }
      BARRIER; __builtin_amdgcn_sched_barrier(0);
      __builtin_amdgcn_s_setprio(1); QUADW(0, 1); __builtin_amdgcn_s_setprio(0);
      BARRIER;
      ldAh(buf, 1);
      if (kt + 2 < NT) { stB(kt + 2, 0, 0); stB(kt + 2, 0, 1); }
      BARRIER; __builtin_amdgcn_sched_barrier(0);
      __builtin_amdgcn_s_setprio(1); QUADW(1, 1); __builtin_amdgcn_s_setprio(0);
      BARRIER;
      if (kt + 2 < NT) { stB(kt + 2, 1, 0); stB(kt + 2, 1, 1); }
      BARRIER; __builtin_amdgcn_sched_barrier(0);
      __builtin_amdgcn_s_setprio(1); QUADW(1, 0); __builtin_amdgcn_s_setprio(0);
      if (kt + 2 < NT) asm volatile("s_waitcnt vmcnt(6)" ::: "memory");
      else asm volatile("s_waitcnt vmcnt(0)" ::: "memory");
      __builtin_amdgcn_sched_barrier(0);
      BARRIER;
    } else {
      ldAh(buf, 0);
      ldBh(bfr[0], buf, 0);
      ldBh(bfr[1], buf, 1);
      if (kt + 1 < NT) { stA(kt + 1, 1, 0); stA(kt + 1, 1, 1); }
      BARRIER; __builtin_amdgcn_sched_barrier(0);
      __builtin_amdgcn_s_setprio(1); QUADN(0); __builtin_amdgcn_s_setprio(0);
      BARRIER;
      ldAh(buf, 1);
      if (kt + 2 < NT) { stA(kt + 2, 0, 0); stA(kt + 2, 0, 1); stB(kt + 2, 0, 0); stB(kt + 2, 1, 0); }
      BARRIER; __builtin_amdgcn_sched_barrier(0);
      __builtin_amdgcn_s_setprio(1); QUADN(1); __builtin_amdgcn_s_setprio(0);
      if (kt + 2 < NT) asm volatile("s_waitcnt vmcnt(4)" ::: "memory");
      else asm volatile("s_waitcnt vmcnt(0)" ::: "memory");
      __builtin_amdgcn_sched_barrier(0);
      BARRIER;
    }
  }

#pragma unroll
  for (int I = 0; I < 2 * NM; ++I) {
#pragma unroll
    for (int J = 0; J < 4; ++J) {
      int mrow, ncol;
      if constexpr (WIDE) {
        mrow = m0 + (I >> 2) * 128 + wr * 64 + (I & 3) * 16 + g * 4;
        ncol = n0 + (J >> 1) * 128 + wc * 32 + (J & 1) * 16 + qr;
      } else {
        mrow = m0 + (I >> 1) * 128 + wr * 32 + (I & 1) * 16 + g * 4;
        ncol = n0 + (J >> 1) * 64 + wc * 32 + (J & 1) * 16 + qr;
      }
      if constexpr (MODE == MODE_QKV) {
        int sel = ncol >> 10, nn = ncol & 1023;
        int h = nn >> 6, dh = nn & 63;
        const float* bptr = (sel == 0) ? bias0 : ((sel == 1) ? bias1 : bias2);
        float bias = bptr[nn];
        if (sel < 2) {
          unsigned short* dst = (sel == 0) ? out_q : out_k;
#pragma unroll
          for (int r = 0; r < 4; ++r) {
            int m = mrow + r; int bb = m >> 10, s = m & 1023;
            dst[(((long)(bb * NHEAD + h)) * S_LEN + s) * DHEAD + dh] = f2bf(acc[I][J][r] + bias);
          }
        } else {
          int m = mrow; int bb = m >> 10, s = m & 1023;
          ushort4 pk;
          pk.x = f2bf(acc[I][J][0] + bias);
          pk.y = f2bf(acc[I][J][1] + bias);
          pk.z = f2bf(acc[I][J][2] + bias);
          pk.w = f2bf(acc[I][J][3] + bias);
          *(ushort4*)&out_vt[(((long)(bb * NHEAD + h)) * DHEAD + dh) * S_LEN + s] = pk;
        }
      } else if constexpr (MODE == MODE_OPROJ) {
        float bias = bias0[ncol];
#pragma unroll
        for (int r = 0; r < 4; ++r) {
          int m = mrow + r; int bb = m >> 10, s = m & 1023;
          long oi = ((long)s * BATCH + bb) * DMODEL + ncol;
          out_f32[oi] = resid[oi] + acc[I][J][r] + bias;
        }
      } else if constexpr (MODE == MODE_FFN1) {
        float bias = bias0[ncol];
#pragma unroll
        for (int r = 0; r < 4; ++r) {
          long m = mrow + r;
          float v = acc[I][J][r] + bias;
          out_bf16[m * (long)N + ncol] = f2bf(v > 0.f ? v : 0.f);
        }
      } else if constexpr (MODE == MODE_PART) {
        unsigned short* pb = out_bf16 + (long)blockIdx.z * 8192 * N;
#pragma unroll
        for (int r = 0; r < 4; ++r) {
          long m = mrow + r;
          pb[m * (long)N + ncol] = f2bf(acc[I][J][r]);
        }
      } else {
        float bias = bias0[ncol];
#pragma unroll
        for (int r = 0; r < 4; ++r) {
          long m = mrow + r;
          long oi = m * (long)N + ncol;
          out_f32[oi] = resid[oi] + acc[I][J][r] + bias;
        }
      }
    }
  }
}

// ---------------- flash attention: 8 waves/block, LDS-staged K/V ----------------
__global__ __launch_bounds__(512, 4) void attn_kernel(
    const unsigned short* __restrict__ qbuf, const unsigned short* __restrict__ kbuf,
    const unsigned short* __restrict__ vtbuf, const float* __restrict__ biasm,
    unsigned short* __restrict__ out) {
  int wave = threadIdx.x >> 6, lane = threadIdx.x & 63;
  int h = blockIdx.y, b = blockIdx.z;
  int q0 = blockIdx.x * 256 + wave * 32;
  long bh = (long)(b * NHEAD + h);
  const unsigned short* Q = qbuf + bh * S_LEN * DHEAD;
  const unsigned short* Kp = kbuf + bh * S_LEN * DHEAD;
  const unsigned short* Vt = vtbuf + bh * DHEAD * S_LEN;
  const float* bm = biasm + (long)b * S_LEN;

  __shared__ unsigned short Ktile[2][64 * 64];
  __shared__ unsigned short Vtile[2][64 * 64];
  __shared__ uint2 Pbuf[8][512];
  __shared__ float AL[8][2][16];
  __shared__ float LI[8][2][16];
  uint2* Pw = Pbuf[wave];

  int qr = lane & 15, g = lane >> 4;

  int srow = wave * 8 + (lane >> 3);
  int scol = (lane & 7) ^ (srow & 7);
  const unsigned short* Ksrc = Kp + (long)srow * DHEAD + scol * 8;
  const unsigned short* Vsrc = Vt + (long)srow * S_LEN + scol * 8;

  bf16x8 qf[2][2];
#pragma unroll
  for (int f = 0; f < 2; ++f)
#pragma unroll
    for (int dhh = 0; dhh < 2; ++dhh)
      qf[f][dhh] = *(const bf16x8*)&Q[(long)(q0 + f * 16 + qr) * DHEAD + dhh * 32 + g * 8];

  f32x4 oacc[2][4];
#pragma unroll
  for (int f = 0; f < 2; ++f)
#pragma unroll
    for (int dt = 0; dt < 4; ++dt) oacc[f][dt] = (f32x4){0.f, 0.f, 0.f, 0.f};
  float m_[2] = {-1e30f, -1e30f}, l_[2] = {0.f, 0.f};

  auto stage = [&](int k0s, int buf) {
    gld_lds16(Ksrc + (long)k0s * DHEAD, (char*)&Ktile[buf][0] + wave * 1024);
    gld_lds16(Vsrc + k0s, (char*)&Vtile[buf][0] + wave * 1024);
  };

  stage(0, 0);
  int cur = 0;
  const int NT = S_LEN / 64;
  for (int t = 0; t < NT; ++t) {
    __syncthreads();
    if (t + 1 < NT) stage((t + 1) * 64, cur ^ 1);

    const char* Kt_l = (const char*)&Ktile[cur][0];
    f32x4 sacc[2][4];
#pragma unroll
    for (int f = 0; f < 2; ++f)
#pragma unroll
      for (int n = 0; n < 4; ++n) sacc[f][n] = (f32x4){0.f, 0.f, 0.f, 0.f};
#pragma unroll
    for (int n = 0; n < 4; ++n)
#pragma unroll
      for (int dhh = 0; dhh < 2; ++dhh) {
        bf16x8 kf = *(const bf16x8*)(Kt_l + (n * 16 + qr) * 128 + (((dhh * 4 + g) ^ (qr & 7)) * 16));
        sacc[0][n] = __builtin_amdgcn_mfma_f32_16x16x32_bf16(kf, qf[0][dhh], sacc[0][n], 0, 0, 0);
        sacc[1][n] = __builtin_amdgcn_mfma_f32_16x16x32_bf16(kf, qf[1][dhh], sacc[1][n], 0, 0, 0);
      }
    float4 bv[4];
#pragma unroll
    for (int n = 0; n < 4; ++n) bv[n] = *(const float4*)&bm[t * 64 + n * 16 + g * 4];

    bf16x8 paf[2][2];
#pragma unroll
    for (int f = 0; f < 2; ++f) {
      float s[16];
#pragma unroll
      for (int n = 0; n < 4; ++n) {
        const float* bvp = (const float*)&bv[n];
#pragma unroll
        for (int r = 0; r < 4; ++r) s[n * 4 + r] = fmaf(sacc[f][n][r], 0.125f, bvp[r]);
      }
      float t8[8], t4[4];
#pragma unroll
      for (int i = 0; i < 8; ++i) t8[i] = fmaxf(s[i], s[i + 8]);
#pragma unroll
      for (int i = 0; i < 4; ++i) t4[i] = fmaxf(t8[i], t8[i + 4]);
      float mx = fmaxf(fmaxf(t4[0], t4[1]), fmaxf(t4[2], t4[3]));
      mx = fmaxf(mx, __shfl_xor(mx, 16));
      mx = fmaxf(mx, __shfl_xor(mx, 32));
      float mnew = fmaxf(m_[f], mx);
      float al = __expf(m_[f] - mnew);
      m_[f] = mnew;
#pragma unroll
      for (int i = 0; i < 16; ++i) s[i] = __expf(s[i] - mnew);
      float u8[8], u4[4];
#pragma unroll
      for (int i = 0; i < 8; ++i) u8[i] = s[i] + s[i + 8];
#pragma unroll
      for (int i = 0; i < 4; ++i) u4[i] = u8[i] + u8[i + 4];
      float ps = (u4[0] + u4[1]) + (u4[2] + u4[3]);
      ps += __shfl_xor(ps, 16);
      ps += __shfl_xor(ps, 32);
      l_[f] = l_[f] * al + ps;
      if (lane < 16) AL[wave][f][lane] = al;
#pragma unroll
      for (int n = 0; n < 4; ++n) {
        unsigned w0, w1;
        asm("v_cvt_pk_bf16_f32 %0, %1, %2" : "=v"(w0) : "v"(s[n * 4 + 0]), "v"(s[n * 4 + 1]));
        asm("v_cvt_pk_bf16_f32 %0, %1, %2" : "=v"(w1) : "v"(s[n * 4 + 2]), "v"(s[n * 4 + 3]));
        Pw[f * 256 + qr * 16 + ((n * 4 + g) ^ qr)] = (uint2){w0, w1};
      }
#pragma unroll
      for (int kb = 0; kb < 2; ++kb) {
        union { uint2 u[2]; bf16x8 v; } p;
        p.u[0] = Pw[f * 256 + qr * 16 + ((kb * 8 + g * 2 + 0) ^ qr)];
        p.u[1] = Pw[f * 256 + qr * 16 + ((kb * 8 + g * 2 + 1) ^ qr)];
        paf[f][kb] = p.v;
      }
    }
#pragma unroll
    for (int f = 0; f < 2; ++f) {
      float4 alv = *(const float4*)&AL[wave][f][g * 4];
      const float* ap = (const float*)&alv;
#pragma unroll
      for (int dt = 0; dt < 4; ++dt)
#pragma unroll
        for (int r = 0; r < 4; ++r) oacc[f][dt][r] *= ap[r];
    }
    const char* Vt_l = (const char*)&Vtile[cur][0];
#pragma unroll
    for (int dt = 0; dt < 4; ++dt)
#pragma unroll
      for (int kb = 0; kb < 2; ++kb) {
        bf16x8 vf = *(const bf16x8*)(Vt_l + (dt * 16 + qr) * 128 + (((kb * 4 + g) ^ (qr & 7)) * 16));
        oacc[0][dt] = __builtin_amdgcn_mfma_f32_16x16x32_bf16(paf[0][kb], vf, oacc[0][dt], 0, 0, 0);
        oacc[1][dt] = __builtin_amdgcn_mfma_f32_16x16x32_bf16(paf[1][kb], vf, oacc[1][dt], 0, 0, 0);
      }
    cur ^= 1;
  }

#pragma unroll
  for (int f = 0; f < 2; ++f)
    if (lane < 16) LI[wave][f][lane] = 1.0f / l_[f];
#pragma unroll
  for (int f = 0; f < 2; ++f) {
    float4 lv = *(const float4*)&LI[wave][f][g * 4];
    const float* lp = (const float*)&lv;
#pragma unroll
    for (int dt = 0; dt < 4; ++dt)
#pragma unroll
      for (int r = 0; r < 4; ++r) {
        int q = q0 + f * 16 + g * 4 + r;
        int dh = dt * 16 + qr;
        out[((long)(b * S_LEN + q)) * DMODEL + h * DHEAD + dh] = f2bf(oacc[f][dt][r] * lp[r]);
      }
  }
}

// ---------------- host launcher ----------------
extern "C" void kernel_launch(void* const* d_in, const int* in_sizes, int n_in,
                              void* d_out, int out_size, void* d_ws, size_t ws_size,
                              hipStream_t stream) {
  const float* x  = (const float*)d_in[0];
  const int* kpm  = (const int*)d_in[1];
  const float* attn_bias = (const float*)d_in[2];
  const float* Wq = (const float*)d_in[3];  const float* bq = (const float*)d_in[4];
  const float* Wk = (const float*)d_in[5];  const float* bk = (const float*)d_in[6];
  const float* Wv = (const float*)d_in[7];  const float* bv = (const float*)d_in[8];
  const float* Wo = (const float*)d_in[9];  const float* bo = (const float*)d_in[10];
  const float* W1 = (const float*)d_in[11]; const float* b1 = (const float*)d_in[12];
  const float* W2 = (const float*)d_in[13]; const float* b2 = (const float*)d_in[14];
  const float* g1 = (const float*)d_in[15]; const float* be1 = (const float*)d_in[16];
  const float* g2 = (const float*)d_in[17]; const float* be2 = (const float*)d_in[18];
  const float* alpha = (const float*)d_in[19];
  float* out = (float*)d_out;

  char* ws = (char*)d_ws;
  size_t off = 0;
  auto alloc = [&](size_t bytes) { void* p = ws + off; off += (bytes + 255) & ~(size_t)255; return p; };
  unsigned short* WqkvT = (unsigned short*)alloc(3072ull * 1024 * 2);
  unsigned short* WoT   = (unsigned short*)alloc(1024ull * 1024 * 2);
  unsigned short* W1T   = (unsigned short*)alloc(4096ull * 1024 * 2);
  unsigned short* W2T   = (unsigned short*)alloc(1024ull * 4096 * 2);
  float* biasm          = (float*)alloc(8192ull * 4);
  float* y1             = (float*)alloc(8192ull * 1024 * 4);
  char* region = (char*)alloc(5ull * 16 * 1024 * 1024);
  unsigned short* x2     = (unsigned short*)(region);
  unsigned short* qb     = (unsigned short*)(region + 16ull * 1024 * 1024);
  unsigned short* kb     = (unsigned short*)(region + 32ull * 1024 * 1024);
  unsigned short* vtb    = (unsigned short*)(region + 48ull * 1024 * 1024);
  unsigned short* attn_o = (unsigned short*)(region + 64ull * 1024 * 1024);
  unsigned short* h2     = (unsigned short*)(region);                        // alias x2 (dead)
  unsigned short* ffn1   = (unsigned short*)(region + 16ull * 1024 * 1024);  // alias qb.. (dead)
  unsigned short* parts  = (unsigned short*)alloc(2ull * 8192 * 1024 * 2);   // split-K partials

  prep_kernel<<<12320, 256, 0, stream>>>(Wq, Wk, Wv, Wo, W1, W2,
                                         WqkvT, WoT, W1T, W2T,
                                         attn_bias, kpm, alpha, biasm);

  ln_kernel<<<8192, 256, 0, stream>>>(x, g1, be1, x2, 1);

  gemm_ph<MODE_QKV, true><<<dim3(3072 / 256, 32), 512, 0, stream>>>(
      x2, WqkvT, 3072, 1024, 16, bq, bk, bv, qb, kb, vtb, nullptr, nullptr, nullptr);

  attn_kernel<<<dim3(S_LEN / 256, NHEAD, BATCH), 512, 0, stream>>>(
      qb, kb, vtb, biasm, attn_o);

  gemm_ph<MODE_OPROJ, false><<<dim3(1024 / 128, 32), 512, 0, stream>>>(
      attn_o, WoT, 1024, 1024, 16, bo, nullptr, nullptr,
      nullptr, nullptr, nullptr, x, y1, nullptr);

  ln_kernel<<<8192, 256, 0, stream>>>(y1, g2, be2, h2, 0);

  gemm_ph<MODE_FFN1, true><<<dim3(4096 / 256, 32), 512, 0, stream>>>(
      h2, W1T, 4096, 1024, 16, b1, nullptr, nullptr,
      nullptr, nullptr, nullptr, nullptr, nullptr, ffn1);

  gemm_ph<MODE_PART, true><<<dim3(1024 / 256, 32, 2), 512, 0, stream>>>(
      ffn1, W2T, 1024, 4096, 32, nullptr, nullptr, nullptr,
      nullptr, nullptr, nullptr, nullptr, nullptr, parts);

  ffn2_reduce<<<8192, 256, 0, stream>>>(parts, parts + 8192ull * 1024, y1, b2, out);
}